// Round 8
// baseline (466.207 us; speedup 1.0000x reference)
//
#include <hip/hip_runtime.h>
#include <hip/hip_bf16.h>
#include <hip/hip_fp16.h>
#include <math.h>

// Edge_Encoder_Residual: 2-layer GATv2 on line-graph + time-MLP + decoder.
// Round 8: xr/res never materialized. gat4<LAYER> computes xr,res for its
// 32 dst nodes in a LDS prologue (L0: f32 W 8KB + x 2KB; L1: fp16 W 16KB +
// h 8KB). pre kernels slim to xlh-only (pre0s: half4 vectorized stores).
// Evidence: r7 pre0v wrote 194MB HBM for 62.5MB of stores (RFO+evict
// amplification), 8us wave lifetimes -> store-path bound, so write less.

#define BLK 256
#define BDST 32            // dsts per fine bucket
#define CDST 256           // dsts per coarse bucket
#define CHUNK 4096         // edges per k_part block
#define FCAP 768           // tag capacity per fine bucket (mean 512)
#define NBC_MAX 512

typedef _Float16 half4v __attribute__((ext_vector_type(4)));
typedef _Float16 half2v __attribute__((ext_vector_type(2)));

__device__ __forceinline__ float leaky02(float x) { return x >= 0.f ? x : 0.2f * x; }
__device__ __forceinline__ float relu(float x) { return x > 0.f ? x : 0.f; }

// ---------- tiny: time embedding + MLP + collapsed decoder matrices ----------
__global__ void k_tiny(const int* __restrict__ t,
                       const float* __restrict__ Wt0, const float* __restrict__ bt0,
                       const float* __restrict__ Wt1, const float* __restrict__ bt1,
                       const float* __restrict__ Wfd, const float* __restrict__ bfd,
                       const float* __restrict__ Wcls, const float* __restrict__ bcls,
                       float* __restrict__ wcomb,   // [96][2]
                       float* __restrict__ bfinal)  // [2]
{
    __shared__ float temb[16];
    int tid = threadIdx.x;
    if (tid == 0) {
        float tf = (float)t[0];
        float e0[16], v1[16];
        const float cexp = -logf(10000.f) / 7.f;
        for (int j = 0; j < 8; ++j) {
            float ang = tf * expf((float)j * cexp);
            e0[j] = sinf(ang);
            e0[8 + j] = cosf(ang);
        }
        for (int i = 0; i < 16; ++i) {
            float a = bt0[i];
            for (int j = 0; j < 16; ++j) a += e0[j] * Wt0[j * 16 + i];
            v1[i] = a / (1.f + expf(-a));
        }
        for (int i = 0; i < 16; ++i) {
            float a = bt1[i];
            for (int j = 0; j < 16; ++j) a += v1[j] * Wt1[j * 16 + i];
            temb[i] = a / (1.f + expf(-a));
        }
    }
    __syncthreads();
    if (tid < 192) {
        int i = tid >> 1, k = tid & 1;
        float a = 0.f;
        for (int j = 0; j < 32; ++j) a += Wfd[i * 32 + j] * Wcls[j * 2 + k];
        wcomb[tid] = a;
    }
    __syncthreads();
    if (tid < 2) {
        float a = bcls[tid];
        for (int j = 0; j < 32; ++j) a += bfd[j] * Wcls[j * 2 + tid];
        for (int d = 0; d < 16; ++d) a += temb[d] * wcomb[(64 + d) * 2 + tid];
        bfinal[tid] = a;
    }
}

// ---------- radix pipeline (unchanged from round 6) ----------
__global__ void k_zeroc(int* __restrict__ ccnt, int NBC)
{
    int gid = blockIdx.x * BLK + threadIdx.x;
    if (gid < NBC) ccnt[gid] = 0;
}

__global__ void k_histc(const int* __restrict__ ei, int E, int NBC,
                        int* __restrict__ ccnt)
{
    __shared__ int h[NBC_MAX];
    int tid = threadIdx.x;
    for (int i = tid; i < NBC; i += BLK) h[i] = 0;
    __syncthreads();
    int e0 = blockIdx.x * CHUNK;
    #pragma unroll
    for (int k = 0; k < CHUNK / BLK; ++k) {
        int e = e0 + tid + k * BLK;
        if (e < E) atomicAdd(&h[ei[E + e] >> 8], 1);
    }
    __syncthreads();
    for (int i = tid; i < NBC; i += BLK) {
        int v = h[i];
        if (v) atomicAdd(&ccnt[i], v);   // fire-and-forget -> pipelines
    }
}

__global__ void k_scan(const int* __restrict__ ccnt, int NBC, int E,
                       int* __restrict__ cbase, int* __restrict__ ccur)
{
    if (threadIdx.x == 0) {
        int acc = 0;
        for (int i = 0; i < NBC; ++i) {
            cbase[i] = acc;
            acc += ccnt[i];
        }
        cbase[NBC] = acc;
    }
    __syncthreads();
    for (int i = threadIdx.x; i < NBC; i += BLK) ccur[i] = cbase[i];
}

__global__ void k_part(const int* __restrict__ ei, int E, int NBC,
                       int* __restrict__ ccur, int* __restrict__ part)
{
    __shared__ int h[NBC_MAX];
    __shared__ int gb[NBC_MAX];
    int tid = threadIdx.x;
    int e0 = blockIdx.x * CHUNK;
    for (int i = tid; i < NBC; i += BLK) h[i] = 0;
    __syncthreads();
    int sv[CHUNK / BLK], dv[CHUNK / BLK];
    #pragma unroll
    for (int k = 0; k < CHUNK / BLK; ++k) {
        int e = e0 + tid + k * BLK;
        if (e < E) {
            sv[k] = ei[e];
            dv[k] = ei[E + e];
            atomicAdd(&h[dv[k] >> 8], 1);
        } else dv[k] = -1;
    }
    __syncthreads();
    for (int i = tid; i < NBC; i += BLK) {
        int v = h[i];
        gb[i] = v ? atomicAdd(&ccur[i], v) : 0;   // block-agg returning atomics
    }
    __syncthreads();
    for (int i = tid; i < NBC; i += BLK) h[i] = gb[i];
    __syncthreads();
    #pragma unroll
    for (int k = 0; k < CHUNK / BLK; ++k) {
        if (dv[k] >= 0) {
            int p = atomicAdd(&h[dv[k] >> 8], 1);   // LDS atomic
            part[p] = (sv[k] << 8) | (dv[k] & 255);
        }
    }
}

__global__ void k_refine(const int* __restrict__ cbase, const int* __restrict__ part,
                         int NBF, int* __restrict__ fbeg, int* __restrict__ fend,
                         int* __restrict__ srcs)
{
    __shared__ int fcnt[8];
    __shared__ int fcur[8];
    int b = blockIdx.x, tid = threadIdx.x;
    int beg = cbase[b], end = cbase[b + 1];
    if (tid < 8) fcnt[tid] = 0;
    __syncthreads();
    for (int k = beg + tid; k < end; k += BLK)
        atomicAdd(&fcnt[(part[k] >> 5) & 7], 1);
    __syncthreads();
    if (tid == 0) {
        int acc = beg;
        #pragma unroll
        for (int f = 0; f < 8; ++f) {
            int fb = b * 8 + f;
            fcur[f] = acc;
            if (fb < NBF) { fbeg[fb] = acc; acc += fcnt[f]; fend[fb] = acc; }
        }
    }
    __syncthreads();
    for (int k = beg + tid; k < end; k += BLK) {
        int tg = part[k];
        int p = atomicAdd(&fcur[(tg >> 5) & 7], 1);
        srcs[p] = ((tg >> 8) << 5) | (tg & 31);
    }
}

// ---------- slim layer-0 precompute: xl only, half4 stores ----------
// Wave = 4 nodes; lane (g,q): node wid*4+g, channels 4q..4q+3.
// Lane q<16 holds x[n][q]; broadcast via shfl. W from L1 (4KB table).
__global__ void k_pre0s(const float* __restrict__ x,
                        const float* __restrict__ Wl, const float* __restrict__ bl,
                        _Float16* __restrict__ xlh, int N)
{
    int wid = (int)(((long long)blockIdx.x * BLK + threadIdx.x) >> 6);
    int lane = threadIdx.x & 63;
    int g = lane >> 4, q = lane & 15;
    int n = wid * 4 + g;
    bool valid = n < N;
    int nn = valid ? n : N - 1;
    float xv = x[(size_t)nn * 16 + q];
    int c0 = q * 4;
    float4 acc = *(const float4*)(bl + c0);
    #pragma unroll
    for (int k = 0; k < 16; ++k) {
        float xk = __shfl(xv, (g << 4) | k, 64);
        float4 wv = *(const float4*)(Wl + k * 64 + c0);
        acc.x = fmaf(xk, wv.x, acc.x);
        acc.y = fmaf(xk, wv.y, acc.y);
        acc.z = fmaf(xk, wv.z, acc.z);
        acc.w = fmaf(xk, wv.w, acc.w);
    }
    if (valid) {
        half4v h;
        h.x = (_Float16)acc.x; h.y = (_Float16)acc.y;
        h.z = (_Float16)acc.z; h.w = (_Float16)acc.w;
        *(half4v*)(xlh + (size_t)n * 64 + c0) = h;
    }
}

// ---------- slim layer-1 precompute: xl only; LDS-staged fp16 Wl + h ----------
__global__ void k_pre1s(const float* __restrict__ h, const float* __restrict__ Wl,
                        _Float16* __restrict__ xlh, int N)
{
    __shared__ _Float16 wlds[32][64][2];   // [kpair][c][klow], 8KB
    __shared__ float hlds[32][64];         // 8KB
    int tid = threadIdx.x;
    int nb = blockIdx.x * 32;
    for (int idx = tid; idx < 4096; idx += BLK) {
        int k = idx >> 6, c = idx & 63;
        wlds[k >> 1][c][k & 1] = (_Float16)Wl[idx];
    }
    for (int idx = tid; idx < 2048; idx += BLK) {
        int i = idx >> 6, c = idx & 63;
        int n = nb + i; if (n >= N) n = N - 1;
        hlds[i][c] = h[(size_t)n * 64 + c];
    }
    __syncthreads();
    int c = tid & 63, w = tid >> 6;
    float al[8];
    #pragma unroll
    for (int i = 0; i < 8; ++i) al[i] = 0.f;
    #pragma unroll 4
    for (int k4 = 0; k4 < 16; ++k4) {
        half2v A = *(const half2v*)&wlds[2 * k4][c][0];
        half2v B = *(const half2v*)&wlds[2 * k4 + 1][c][0];
        float l0 = (float)A.x, l1 = (float)A.y, l2 = (float)B.x, l3 = (float)B.y;
        #pragma unroll
        for (int i = 0; i < 8; ++i) {
            float4 hv = *(const float4*)&hlds[w * 8 + i][4 * k4];  // broadcast
            al[i] += hv.x * l0 + hv.y * l1 + hv.z * l2 + hv.w * l3;
        }
    }
    #pragma unroll
    for (int i = 0; i < 8; ++i) {
        int n = nb + w * 8 + i;
        if (n < N) xlh[(size_t)n * 64 + c] = (_Float16)al[i];
    }
}

// ---------- fused GATv2 + on-the-fly xr/res: one 256-thr block per bucket ----
// LAYER 0: xin = x (K=16), f32 W staged; epilogue bias0, writes hout.
// LAYER 1: xin = h (K=64), fp16 W staged; epilogue fused decoder.
template <int LAYER>
__global__ void k_gat4(const int* __restrict__ fbeg, const int* __restrict__ fend,
                       const int* __restrict__ srcs,
                       const _Float16* __restrict__ xlh,
                       const float* __restrict__ xin,
                       const float* __restrict__ Wr, const float* __restrict__ brv,
                       const float* __restrict__ Wres, const float* __restrict__ bres,
                       const float* __restrict__ att, const float* __restrict__ bias,
                       float* __restrict__ hout,
                       const float* __restrict__ cond, const float* __restrict__ wcomb,
                       const float* __restrict__ bfinal, float* __restrict__ out,
                       int N)
{
    __shared__ float fsm[LAYER == 0 ? 2688 : 6208];
    __shared__ int lh[BDST];
    __shared__ int rp[BDST + 1];
    __shared__ int cc[BDST];
    __shared__ int tags[FCAP];

    int b = blockIdx.x;
    int tid = threadIdx.x;
    int nb = b * BDST;

    // ---- stage node rows + weight tiles ----
    if constexpr (LAYER == 0) {
        // xst[32][16] | Wrst[16][64] | Wsst[16][64] | brs[64] | bss[64]
        for (int idx = tid; idx < 512; idx += BLK) {
            int r = idx >> 4, k = idx & 15;
            int n = nb + r; if (n >= N) n = N - 1;
            fsm[idx] = xin[(size_t)n * 16 + k];
        }
        for (int idx = tid; idx < 1024; idx += BLK) {
            fsm[512 + idx] = Wr[idx];
            fsm[1536 + idx] = Wres[idx];
        }
        if (tid < 64) { fsm[2560 + tid] = brv[tid]; fsm[2624 + tid] = bres[tid]; }
    } else {
        // hst[32][64] | W16r[64][64] half | W16s[64][64] half | bss[64]
        _Float16* W16r = (_Float16*)(fsm + 2048);
        _Float16* W16s = (_Float16*)(fsm + 4096);
        for (int idx = tid; idx < 2048; idx += BLK) {
            int r = idx >> 6, k = idx & 63;
            int n = nb + r; if (n >= N) n = N - 1;
            fsm[idx] = xin[(size_t)n * 64 + k];
        }
        for (int idx = tid; idx < 4096; idx += BLK) {
            W16r[idx] = (_Float16)Wr[idx];
            W16s[idx] = (_Float16)Wres[idx];
        }
        if (tid < 64) fsm[6144 + tid] = bres[tid];
    }
    if (tid < BDST) lh[tid] = 0;
    __syncthreads();

    // ---- counting sort by dst-low ----
    int beg = fbeg[b];
    int nE = fend[b] - beg; if (nE > FCAP) nE = FCAP;
    for (int k = tid; k < nE; k += BLK) atomicAdd(&lh[srcs[beg + k] & 31], 1);
    __syncthreads();
    if (tid == 0) {
        int acc = 0; rp[0] = 0;
        #pragma unroll
        for (int i = 0; i < BDST; ++i) { acc += lh[i]; rp[i + 1] = acc; }
    }
    __syncthreads();
    if (tid < BDST) cc[tid] = rp[tid];
    __syncthreads();
    for (int k = tid; k < nE; k += BLK) {
        int tg = srcs[beg + k];
        int r = atomicAdd(&cc[tg & 31], 1);
        tags[r] = tg >> 5;
    }
    __syncthreads();

    int lane = tid & 63, w = tid >> 6;
    int g = lane >> 4, q = lane & 15;
    int c0 = q * 4;
    float4 a4 = *(const float4*)(att + c0);

    // ---- prologue: compute xr4 / res4 for this thread's 2 dst rows ----
    float4 xr4[2], r4[2];
    #pragma unroll
    for (int rep = 0; rep < 2; ++rep) {
        int dlow = w * 8 + rep * 4 + g;
        float4 accr, accs;
        if constexpr (LAYER == 0) {
            accr = *(const float4*)(fsm + 2560 + c0);
            accs = *(const float4*)(fsm + 2624 + c0);
            #pragma unroll
            for (int k = 0; k < 16; ++k) {
                float xk = fsm[dlow * 16 + k];
                float4 wr = *(const float4*)(fsm + 512 + k * 64 + c0);
                float4 wsv = *(const float4*)(fsm + 1536 + k * 64 + c0);
                accr.x = fmaf(xk, wr.x, accr.x);
                accr.y = fmaf(xk, wr.y, accr.y);
                accr.z = fmaf(xk, wr.z, accr.z);
                accr.w = fmaf(xk, wr.w, accr.w);
                accs.x = fmaf(xk, wsv.x, accs.x);
                accs.y = fmaf(xk, wsv.y, accs.y);
                accs.z = fmaf(xk, wsv.z, accs.z);
                accs.w = fmaf(xk, wsv.w, accs.w);
            }
        } else {
            const _Float16* W16r = (const _Float16*)(fsm + 2048);
            const _Float16* W16s = (const _Float16*)(fsm + 4096);
            accr.x = accr.y = accr.z = accr.w = 0.f;
            accs = *(const float4*)(fsm + 6144 + c0);
            #pragma unroll 8
            for (int k = 0; k < 64; ++k) {
                float hk = fsm[dlow * 64 + k];
                half4v wr = *(const half4v*)(W16r + k * 64 + c0);
                half4v wsv = *(const half4v*)(W16s + k * 64 + c0);
                accr.x = fmaf(hk, (float)wr.x, accr.x);
                accr.y = fmaf(hk, (float)wr.y, accr.y);
                accr.z = fmaf(hk, (float)wr.z, accr.z);
                accr.w = fmaf(hk, (float)wr.w, accr.w);
                accs.x = fmaf(hk, (float)wsv.x, accs.x);
                accs.y = fmaf(hk, (float)wsv.y, accs.y);
                accs.z = fmaf(hk, (float)wsv.z, accs.z);
                accs.w = fmaf(hk, (float)wsv.w, accs.w);
            }
        }
        xr4[rep] = accr;
        r4[rep].x = relu(accs.x);
        r4[rep].y = relu(accs.y);
        r4[rep].z = relu(accs.z);
        r4[rep].w = relu(accs.w);
    }

    // ---- edge loop per rep (online softmax, 1-deep prefetch) ----
    #pragma unroll
    for (int rep = 0; rep < 2; ++rep) {
        int dlow = w * 8 + rep * 4 + g;
        int node = nb + dlow;
        bool nvalid = node < N;
        int n = nvalid ? node : 0;
        float4 xrv = xr4[rep];

        half4v hs = *(const half4v*)(xlh + (size_t)n * 64 + c0);
        float s0 = (float)hs.x, s1 = (float)hs.y, s2 = (float)hs.z, s3 = (float)hs.w;
        float lv = leaky02(s0 + xrv.x) * a4.x + leaky02(s1 + xrv.y) * a4.y
                 + leaky02(s2 + xrv.z) * a4.z + leaky02(s3 + xrv.w) * a4.w;
        lv += __shfl_xor(lv, 1, 8);
        lv += __shfl_xor(lv, 2, 8);
        lv += __shfl_xor(lv, 4, 8);

        float m = lv, den = 1.f;
        float ac0 = s0, ac1 = s1, ac2 = s2, ac3 = s3;

        int deg = nvalid ? (rp[dlow + 1] - rp[dlow]) : 0;
        int base = nvalid ? rp[dlow] : 0;

        int t1 = max(deg, __shfl_xor(deg, 16, 64));
        int wavemax = max(t1, __shfl_xor(t1, 32, 64));

        int s_nxt = (deg > 0) ? tags[base] : n;
        half4v h_nxt = *(const half4v*)(xlh + (size_t)s_nxt * 64 + c0);

        for (int j = 0; j < wavemax; ++j) {
            bool act = j < deg;
            half4v hx = h_nxt;
            int nxt = (j + 1 < deg) ? tags[base + j + 1] : n;
            h_nxt = *(const half4v*)(xlh + (size_t)nxt * 64 + c0);

            float x0 = (float)hx.x, x1 = (float)hx.y, x2 = (float)hx.z, x3 = (float)hx.w;
            float e = leaky02(x0 + xrv.x) * a4.x + leaky02(x1 + xrv.y) * a4.y
                    + leaky02(x2 + xrv.z) * a4.z + leaky02(x3 + xrv.w) * a4.w;
            e += __shfl_xor(e, 1, 8);
            e += __shfl_xor(e, 2, 8);
            e += __shfl_xor(e, 4, 8);
            if (!act) e = -1e30f;
            float mn = fmaxf(m, e);
            float sc = __expf(m - mn);
            float ex = __expf(e - mn);
            den = den * sc + ex;
            ac0 = ac0 * sc + ex * x0;
            ac1 = ac1 * sc + ex * x1;
            ac2 = ac2 * sc + ex * x2;
            ac3 = ac3 * sc + ex * x3;
            m = mn;
        }

        float inv = 1.f / den;
        float h0, h1, h2, h3;
        if constexpr (LAYER == 0) {
            float4 b4 = *(const float4*)(bias + c0);
            h0 = relu(ac0 * inv + b4.x) + r4[rep].x;
            h1 = relu(ac1 * inv + b4.y) + r4[rep].y;
            h2 = relu(ac2 * inv + b4.z) + r4[rep].z;
            h3 = relu(ac3 * inv + b4.w) + r4[rep].w;
        } else {
            h0 = relu(ac0 * inv) + r4[rep].x;
            h1 = relu(ac1 * inv) + r4[rep].y;
            h2 = relu(ac2 * inv) + r4[rep].z;
            h3 = relu(ac3 * inv) + r4[rep].w;
        }

        if constexpr (LAYER == 0) {
            if (nvalid) {
                float4 o; o.x = h0; o.y = h1; o.z = h2; o.w = h3;
                *(float4*)(hout + (size_t)n * 64 + c0) = o;
            }
        } else {
            float p0 = h0 * wcomb[(c0 + 0) * 2] + h1 * wcomb[(c0 + 1) * 2]
                     + h2 * wcomb[(c0 + 2) * 2] + h3 * wcomb[(c0 + 3) * 2];
            float p1 = h0 * wcomb[(c0 + 0) * 2 + 1] + h1 * wcomb[(c0 + 1) * 2 + 1]
                     + h2 * wcomb[(c0 + 2) * 2 + 1] + h3 * wcomb[(c0 + 3) * 2 + 1];
            if (q < 4) {
                float4 c4 = *(const float4*)(cond + (size_t)n * 16 + q * 4);
                int d0 = 80 + q * 4;
                p0 += c4.x * wcomb[(d0 + 0) * 2] + c4.y * wcomb[(d0 + 1) * 2]
                    + c4.z * wcomb[(d0 + 2) * 2] + c4.w * wcomb[(d0 + 3) * 2];
                p1 += c4.x * wcomb[(d0 + 0) * 2 + 1] + c4.y * wcomb[(d0 + 1) * 2 + 1]
                    + c4.z * wcomb[(d0 + 2) * 2 + 1] + c4.w * wcomb[(d0 + 3) * 2 + 1];
            }
            #pragma unroll
            for (int off = 1; off < 16; off <<= 1) {
                p0 += __shfl_xor(p0, off, 16);
                p1 += __shfl_xor(p1, off, 16);
            }
            if (q == 0 && nvalid) {
                out[(size_t)n * 2] = p0 + bfinal[0];
                out[(size_t)n * 2 + 1] = p1 + bfinal[1];
            }
        }
    }
}

static inline int gblk(long long threads) { return (int)((threads + BLK - 1) / BLK); }

extern "C" void kernel_launch(void* const* d_in, const int* in_sizes, int n_in,
                              void* d_out, int out_size, void* d_ws, size_t ws_size,
                              hipStream_t stream) {
    const float* x     = (const float*)d_in[0];
    const int*   ei    = (const int*)d_in[1];
    const int*   t     = (const int*)d_in[2];
    const float* cond  = (const float*)d_in[3];
    const float* Wl0   = (const float*)d_in[4];
    const float* bl0   = (const float*)d_in[5];
    const float* Wr0   = (const float*)d_in[6];
    const float* br0   = (const float*)d_in[7];
    const float* att0  = (const float*)d_in[8];
    const float* bias0 = (const float*)d_in[9];
    const float* Wres0 = (const float*)d_in[10];
    const float* bres0 = (const float*)d_in[11];
    const float* Wl1   = (const float*)d_in[12];
    const float* Wr1   = (const float*)d_in[13];
    const float* att1  = (const float*)d_in[14];
    const float* Wres1 = (const float*)d_in[15];
    const float* bres1 = (const float*)d_in[16];
    const float* Wt0   = (const float*)d_in[17];
    const float* bt0   = (const float*)d_in[18];
    const float* Wt1   = (const float*)d_in[19];
    const float* bt1   = (const float*)d_in[20];
    const float* Wfd   = (const float*)d_in[21];
    const float* bfd   = (const float*)d_in[22];
    const float* Wcls  = (const float*)d_in[23];
    const float* bcls  = (const float*)d_in[24];
    float* out = (float*)d_out;

    const int N   = in_sizes[0] / 16;
    const int E   = in_sizes[1] / 2;
    const int NBC = (N + CDST - 1) / CDST;
    const int NBF = (N + BDST - 1) / BDST;

    float* ws = (float*)d_ws;
    size_t o = 0;
    float* hbuf  = ws + o; o += (size_t)N * 64;
    _Float16* xlh = (_Float16*)(ws + o); o += (size_t)N * 32;  // 16B-aligned
    float* wcomb = ws + o; o += 192;
    float* bfin  = ws + o; o += 2;
    int* iws     = (int*)(ws + o);
    size_t io = 0;
    int* ccnt  = iws + io; io += NBC_MAX;
    int* cbase = iws + io; io += NBC_MAX + 1;
    int* ccur  = iws + io; io += NBC_MAX;
    int* fbeg  = iws + io; io += NBF;
    int* fend  = iws + io; io += NBF;
    int* part  = iws + io; io += E;
    int* srcs  = iws + io; io += E;

    const int partBlocks = (E + CHUNK - 1) / CHUNK;

    // tiny decoder/time precompute
    k_tiny<<<1, BLK, 0, stream>>>(t, Wt0, bt0, Wt1, bt1, Wfd, bfd, Wcls, bcls, wcomb, bfin);

    // ---- radix partition by destination ----
    k_zeroc<<<gblk(NBC), BLK, 0, stream>>>(ccnt, NBC);
    k_histc<<<partBlocks, BLK, 0, stream>>>(ei, E, NBC, ccnt);
    k_scan<<<1, BLK, 0, stream>>>(ccnt, NBC, E, cbase, ccur);
    k_part<<<partBlocks, BLK, 0, stream>>>(ei, E, NBC, ccur, part);
    k_refine<<<NBC, BLK, 0, stream>>>(cbase, part, NBF, fbeg, fend, srcs);

    // ---- layer 0 ----
    k_pre0s<<<gblk((long long)((N + 3) / 4) * 64), BLK, 0, stream>>>(x, Wl0, bl0, xlh, N);
    k_gat4<0><<<NBF, BLK, 0, stream>>>(fbeg, fend, srcs, xlh, x, Wr0, br0, Wres0, bres0,
                                       att0, bias0, hbuf, nullptr, nullptr, nullptr, nullptr, N);

    // ---- layer 1 (decoder fused) ----
    k_pre1s<<<(N + 31) / 32, BLK, 0, stream>>>(hbuf, Wl1, xlh, N);
    k_gat4<1><<<NBF, BLK, 0, stream>>>(fbeg, fend, srcs, xlh, hbuf, Wr1, nullptr, Wres1, bres1,
                                       att1, nullptr, nullptr, cond, wcomb, bfin, out, N);
}

// Round 9
// 346.897 us; speedup vs baseline: 1.3439x; 1.3439x over previous
//
#include <hip/hip_runtime.h>
#include <hip/hip_bf16.h>
#include <hip/hip_fp16.h>
#include <math.h>

// Edge_Encoder_Residual: 2-layer GATv2 on line-graph + time-MLP + decoder.
// Round 9: revert r8's mega-fusion (scratch-spill regression: FETCH+WRITE
// both ~340MB symmetric = spill/fill). Base = r7 structure. Change: xr/res
// stored as fp16 (pre kernels were store-bytes-bound: 84us @ 3x write
// amplification), pre0 rewritten slim (4 nodes/wave, L1-resident W,
// coalesced half4 stores). gat3 reads xr/res as half4.

#define BLK 256
#define BDST 32            // dsts per fine bucket
#define CDST 256           // dsts per coarse bucket
#define CHUNK 4096         // edges per k_part block
#define FCAP 768           // tag capacity per fine bucket (mean 512)
#define NBC_MAX 512

typedef _Float16 half4v __attribute__((ext_vector_type(4)));
typedef _Float16 half2v __attribute__((ext_vector_type(2)));

__device__ __forceinline__ float leaky02(float x) { return x >= 0.f ? x : 0.2f * x; }
__device__ __forceinline__ float relu(float x) { return x > 0.f ? x : 0.f; }

// ---------- tiny: time embedding + MLP + collapsed decoder matrices ----------
__global__ void k_tiny(const int* __restrict__ t,
                       const float* __restrict__ Wt0, const float* __restrict__ bt0,
                       const float* __restrict__ Wt1, const float* __restrict__ bt1,
                       const float* __restrict__ Wfd, const float* __restrict__ bfd,
                       const float* __restrict__ Wcls, const float* __restrict__ bcls,
                       float* __restrict__ wcomb,   // [96][2]
                       float* __restrict__ bfinal)  // [2]
{
    __shared__ float temb[16];
    int tid = threadIdx.x;
    if (tid == 0) {
        float tf = (float)t[0];
        float e0[16], v1[16];
        const float cexp = -logf(10000.f) / 7.f;
        for (int j = 0; j < 8; ++j) {
            float ang = tf * expf((float)j * cexp);
            e0[j] = sinf(ang);
            e0[8 + j] = cosf(ang);
        }
        for (int i = 0; i < 16; ++i) {
            float a = bt0[i];
            for (int j = 0; j < 16; ++j) a += e0[j] * Wt0[j * 16 + i];
            v1[i] = a / (1.f + expf(-a));
        }
        for (int i = 0; i < 16; ++i) {
            float a = bt1[i];
            for (int j = 0; j < 16; ++j) a += v1[j] * Wt1[j * 16 + i];
            temb[i] = a / (1.f + expf(-a));
        }
    }
    __syncthreads();
    if (tid < 192) {
        int i = tid >> 1, k = tid & 1;
        float a = 0.f;
        for (int j = 0; j < 32; ++j) a += Wfd[i * 32 + j] * Wcls[j * 2 + k];
        wcomb[tid] = a;
    }
    __syncthreads();
    if (tid < 2) {
        float a = bcls[tid];
        for (int j = 0; j < 32; ++j) a += bfd[j] * Wcls[j * 2 + tid];
        for (int d = 0; d < 16; ++d) a += temb[d] * wcomb[(64 + d) * 2 + tid];
        bfinal[tid] = a;
    }
}

// ---------- radix pipeline (unchanged since round 6) ----------
__global__ void k_zeroc(int* __restrict__ ccnt, int NBC)
{
    int gid = blockIdx.x * BLK + threadIdx.x;
    if (gid < NBC) ccnt[gid] = 0;
}

__global__ void k_histc(const int* __restrict__ ei, int E, int NBC,
                        int* __restrict__ ccnt)
{
    __shared__ int h[NBC_MAX];
    int tid = threadIdx.x;
    for (int i = tid; i < NBC; i += BLK) h[i] = 0;
    __syncthreads();
    int e0 = blockIdx.x * CHUNK;
    #pragma unroll
    for (int k = 0; k < CHUNK / BLK; ++k) {
        int e = e0 + tid + k * BLK;
        if (e < E) atomicAdd(&h[ei[E + e] >> 8], 1);
    }
    __syncthreads();
    for (int i = tid; i < NBC; i += BLK) {
        int v = h[i];
        if (v) atomicAdd(&ccnt[i], v);   // fire-and-forget -> pipelines
    }
}

__global__ void k_scan(const int* __restrict__ ccnt, int NBC, int E,
                       int* __restrict__ cbase, int* __restrict__ ccur)
{
    if (threadIdx.x == 0) {
        int acc = 0;
        for (int i = 0; i < NBC; ++i) {
            cbase[i] = acc;
            acc += ccnt[i];
        }
        cbase[NBC] = acc;
    }
    __syncthreads();
    for (int i = threadIdx.x; i < NBC; i += BLK) ccur[i] = cbase[i];
}

__global__ void k_part(const int* __restrict__ ei, int E, int NBC,
                       int* __restrict__ ccur, int* __restrict__ part)
{
    __shared__ int h[NBC_MAX];
    __shared__ int gb[NBC_MAX];
    int tid = threadIdx.x;
    int e0 = blockIdx.x * CHUNK;
    for (int i = tid; i < NBC; i += BLK) h[i] = 0;
    __syncthreads();
    int sv[CHUNK / BLK], dv[CHUNK / BLK];
    #pragma unroll
    for (int k = 0; k < CHUNK / BLK; ++k) {
        int e = e0 + tid + k * BLK;
        if (e < E) {
            sv[k] = ei[e];
            dv[k] = ei[E + e];
            atomicAdd(&h[dv[k] >> 8], 1);
        } else dv[k] = -1;
    }
    __syncthreads();
    for (int i = tid; i < NBC; i += BLK) {
        int v = h[i];
        gb[i] = v ? atomicAdd(&ccur[i], v) : 0;   // block-agg returning atomics
    }
    __syncthreads();
    for (int i = tid; i < NBC; i += BLK) h[i] = gb[i];
    __syncthreads();
    #pragma unroll
    for (int k = 0; k < CHUNK / BLK; ++k) {
        if (dv[k] >= 0) {
            int p = atomicAdd(&h[dv[k] >> 8], 1);   // LDS atomic
            part[p] = (sv[k] << 8) | (dv[k] & 255);
        }
    }
}

__global__ void k_refine(const int* __restrict__ cbase, const int* __restrict__ part,
                         int NBF, int* __restrict__ fbeg, int* __restrict__ fend,
                         int* __restrict__ srcs)
{
    __shared__ int fcnt[8];
    __shared__ int fcur[8];
    int b = blockIdx.x, tid = threadIdx.x;
    int beg = cbase[b], end = cbase[b + 1];
    if (tid < 8) fcnt[tid] = 0;
    __syncthreads();
    for (int k = beg + tid; k < end; k += BLK)
        atomicAdd(&fcnt[(part[k] >> 5) & 7], 1);
    __syncthreads();
    if (tid == 0) {
        int acc = beg;
        #pragma unroll
        for (int f = 0; f < 8; ++f) {
            int fb = b * 8 + f;
            fcur[f] = acc;
            if (fb < NBF) { fbeg[fb] = acc; acc += fcnt[f]; fend[fb] = acc; }
        }
    }
    __syncthreads();
    for (int k = beg + tid; k < end; k += BLK) {
        int tg = part[k];
        int p = atomicAdd(&fcur[(tg >> 5) & 7], 1);
        srcs[p] = ((tg >> 8) << 5) | (tg & 31);
    }
}

// ---------- layer 0 precompute: xl, xr, res — all fp16, 4 nodes/wave ----------
// Lane (g,q): node wid*4+g, channels 4q..4q+3. W tables (12KB f32) are
// L1-resident; x broadcast via shfl. Stores: half4 = 128B/row contiguous.
__global__ void k_pre0f(const float* __restrict__ x,
                        const float* __restrict__ Wl, const float* __restrict__ bl,
                        const float* __restrict__ Wr, const float* __restrict__ br,
                        const float* __restrict__ Wres, const float* __restrict__ bres,
                        _Float16* __restrict__ xlh, _Float16* __restrict__ xr16,
                        _Float16* __restrict__ res16, int N)
{
    int wid = (int)(((long long)blockIdx.x * BLK + threadIdx.x) >> 6);
    int lane = threadIdx.x & 63;
    int g = lane >> 4, q = lane & 15;
    int n = wid * 4 + g;
    bool valid = n < N;
    int nn = valid ? n : N - 1;
    float xv = x[(size_t)nn * 16 + q];
    int c0 = q * 4;
    float4 accl = *(const float4*)(bl + c0);
    float4 accr = *(const float4*)(br + c0);
    float4 accs = *(const float4*)(bres + c0);
    #pragma unroll
    for (int k = 0; k < 16; ++k) {
        float xk = __shfl(xv, (g << 4) | k, 64);
        float4 wl = *(const float4*)(Wl + k * 64 + c0);
        float4 wr = *(const float4*)(Wr + k * 64 + c0);
        float4 wsv = *(const float4*)(Wres + k * 64 + c0);
        accl.x = fmaf(xk, wl.x, accl.x);
        accl.y = fmaf(xk, wl.y, accl.y);
        accl.z = fmaf(xk, wl.z, accl.z);
        accl.w = fmaf(xk, wl.w, accl.w);
        accr.x = fmaf(xk, wr.x, accr.x);
        accr.y = fmaf(xk, wr.y, accr.y);
        accr.z = fmaf(xk, wr.z, accr.z);
        accr.w = fmaf(xk, wr.w, accr.w);
        accs.x = fmaf(xk, wsv.x, accs.x);
        accs.y = fmaf(xk, wsv.y, accs.y);
        accs.z = fmaf(xk, wsv.z, accs.z);
        accs.w = fmaf(xk, wsv.w, accs.w);
    }
    if (valid) {
        size_t base = (size_t)n * 64 + c0;
        half4v hl, hr, hs;
        hl.x = (_Float16)accl.x; hl.y = (_Float16)accl.y;
        hl.z = (_Float16)accl.z; hl.w = (_Float16)accl.w;
        hr.x = (_Float16)accr.x; hr.y = (_Float16)accr.y;
        hr.z = (_Float16)accr.z; hr.w = (_Float16)accr.w;
        hs.x = (_Float16)relu(accs.x); hs.y = (_Float16)relu(accs.y);
        hs.z = (_Float16)relu(accs.z); hs.w = (_Float16)relu(accs.w);
        *(half4v*)(xlh + base) = hl;
        *(half4v*)(xr16 + base) = hr;
        *(half4v*)(res16 + base) = hs;
    }
}

// ---------- layer 1 precompute: LDS-staged fp16 W + LDS h broadcast ----------
// Outputs xl, xr, res all fp16. Block = 4 waves, 32 nodes. LDS 32KB.
__global__ void k_pre1w(const float* __restrict__ h,
                        const float* __restrict__ Wl, const float* __restrict__ Wr,
                        const float* __restrict__ Wres, const float* __restrict__ bres,
                        _Float16* __restrict__ xlh, _Float16* __restrict__ xr16,
                        _Float16* __restrict__ res16, int N)
{
    __shared__ _Float16 wlds[32][3][64][2];
    __shared__ float hlds[32][64];
    int tid = threadIdx.x;
    int nb = blockIdx.x * 32;

    for (int idx = tid; idx < 3 * 4096; idx += BLK) {
        int m = idx >> 12, rem = idx & 4095;
        int k = rem >> 6, c = rem & 63;
        const float* W = (m == 0) ? Wl : (m == 1) ? Wr : Wres;
        wlds[k >> 1][m][c][k & 1] = (_Float16)W[k * 64 + c];
    }
    for (int idx = tid; idx < 32 * 64; idx += BLK) {
        int i = idx >> 6, c = idx & 63;
        int n = nb + i; if (n >= N) n = N - 1;
        hlds[i][c] = h[(size_t)n * 64 + c];
    }
    __syncthreads();

    int c = tid & 63, w = tid >> 6;
    float al[8], ar[8], as[8];
    float vbs = bres[c];
    #pragma unroll
    for (int i = 0; i < 8; ++i) { al[i] = 0.f; ar[i] = 0.f; as[i] = vbs; }

    #pragma unroll 4
    for (int k4 = 0; k4 < 16; ++k4) {
        half2v wlA = *(const half2v*)&wlds[2 * k4][0][c][0];
        half2v wrA = *(const half2v*)&wlds[2 * k4][1][c][0];
        half2v wsA = *(const half2v*)&wlds[2 * k4][2][c][0];
        half2v wlB = *(const half2v*)&wlds[2 * k4 + 1][0][c][0];
        half2v wrB = *(const half2v*)&wlds[2 * k4 + 1][1][c][0];
        half2v wsB = *(const half2v*)&wlds[2 * k4 + 1][2][c][0];
        float l0 = (float)wlA.x, l1 = (float)wlA.y, l2 = (float)wlB.x, l3 = (float)wlB.y;
        float r0 = (float)wrA.x, r1 = (float)wrA.y, r2 = (float)wrB.x, r3 = (float)wrB.y;
        float s0 = (float)wsA.x, s1 = (float)wsA.y, s2 = (float)wsB.x, s3 = (float)wsB.y;
        #pragma unroll
        for (int i = 0; i < 8; ++i) {
            float4 hv = *(const float4*)&hlds[w * 8 + i][4 * k4];   // broadcast
            al[i] += hv.x * l0 + hv.y * l1 + hv.z * l2 + hv.w * l3;
            ar[i] += hv.x * r0 + hv.y * r1 + hv.z * r2 + hv.w * r3;
            as[i] += hv.x * s0 + hv.y * s1 + hv.z * s2 + hv.w * s3;
        }
    }
    #pragma unroll
    for (int i = 0; i < 8; ++i) {
        int n = nb + w * 8 + i;
        if (n < N) {
            xlh[(size_t)n * 64 + c]   = (_Float16)al[i];
            xr16[(size_t)n * 64 + c]  = (_Float16)ar[i];
            res16[(size_t)n * 64 + c] = (_Float16)relu(as[i]);
        }
    }
}

// ---------- fused GATv2: one 256-thr block (4 waves) per 32-dst fine bucket ----
template <bool DEC>
__global__ void k_gat3(const int* __restrict__ fbeg, const int* __restrict__ fend,
                       const int* __restrict__ srcs,
                       const _Float16* __restrict__ xlh, const _Float16* __restrict__ xr16,
                       const float* __restrict__ att, const float* __restrict__ bias,
                       const _Float16* __restrict__ res16,
                       float* __restrict__ hout,
                       const float* __restrict__ cond, const float* __restrict__ wcomb,
                       const float* __restrict__ bfinal, float* __restrict__ out,
                       int N)
{
    __shared__ int lh[BDST];
    __shared__ int rp[BDST + 1];
    __shared__ int cc[BDST];
    __shared__ int tags[FCAP];

    int b = blockIdx.x;
    int tid = threadIdx.x;
    int beg = fbeg[b];
    int nE = fend[b] - beg; if (nE > FCAP) nE = FCAP;

    if (tid < BDST) lh[tid] = 0;
    __syncthreads();
    for (int k = tid; k < nE; k += BLK) atomicAdd(&lh[srcs[beg + k] & 31], 1);
    __syncthreads();
    if (tid == 0) {
        int acc = 0;
        rp[0] = 0;
        #pragma unroll
        for (int i = 0; i < BDST; ++i) { acc += lh[i]; rp[i + 1] = acc; }
    }
    __syncthreads();
    if (tid < BDST) cc[tid] = rp[tid];
    __syncthreads();
    for (int k = tid; k < nE; k += BLK) {
        int tg = srcs[beg + k];
        int r = atomicAdd(&cc[tg & 31], 1);
        tags[r] = tg >> 5;
    }
    __syncthreads();

    int lane = tid & 63, w = tid >> 6;
    int g = lane >> 4, q = lane & 15;
    int c0 = q * 4;
    float4 a4 = *(const float4*)(att + c0);

    #pragma unroll
    for (int rep = 0; rep < 2; ++rep) {
        int dlow = w * 8 + rep * 4 + g;
        int node = b * BDST + dlow;
        bool nvalid = node < N;
        int n = nvalid ? node : 0;

        half4v xrh = *(const half4v*)(xr16 + (size_t)n * 64 + c0);
        float xrx = (float)xrh.x, xry = (float)xrh.y, xrz = (float)xrh.z, xrw = (float)xrh.w;

        half4v hs = *(const half4v*)(xlh + (size_t)n * 64 + c0);
        float s0 = (float)hs.x, s1 = (float)hs.y, s2 = (float)hs.z, s3 = (float)hs.w;
        float lv = leaky02(s0 + xrx) * a4.x + leaky02(s1 + xry) * a4.y
                 + leaky02(s2 + xrz) * a4.z + leaky02(s3 + xrw) * a4.w;
        lv += __shfl_xor(lv, 1, 8);
        lv += __shfl_xor(lv, 2, 8);
        lv += __shfl_xor(lv, 4, 8);

        float m = lv, den = 1.f;
        float ac0 = s0, ac1 = s1, ac2 = s2, ac3 = s3;

        int deg = nvalid ? (rp[dlow + 1] - rp[dlow]) : 0;
        int base = nvalid ? rp[dlow] : 0;

        int t1 = max(deg, __shfl_xor(deg, 16, 64));
        int wavemax = max(t1, __shfl_xor(t1, 32, 64));

        int s_nxt = (deg > 0) ? tags[base] : n;
        half4v h_nxt = *(const half4v*)(xlh + (size_t)s_nxt * 64 + c0);

        for (int j = 0; j < wavemax; ++j) {
            bool act = j < deg;
            half4v hx = h_nxt;
            int nxt = (j + 1 < deg) ? tags[base + j + 1] : n;
            h_nxt = *(const half4v*)(xlh + (size_t)nxt * 64 + c0);

            float x0 = (float)hx.x, x1 = (float)hx.y, x2 = (float)hx.z, x3 = (float)hx.w;
            float e = leaky02(x0 + xrx) * a4.x + leaky02(x1 + xry) * a4.y
                    + leaky02(x2 + xrz) * a4.z + leaky02(x3 + xrw) * a4.w;
            e += __shfl_xor(e, 1, 8);
            e += __shfl_xor(e, 2, 8);
            e += __shfl_xor(e, 4, 8);
            if (!act) e = -1e30f;
            float mn = fmaxf(m, e);
            float sc = __expf(m - mn);
            float ex = __expf(e - mn);
            den = den * sc + ex;
            ac0 = ac0 * sc + ex * x0;
            ac1 = ac1 * sc + ex * x1;
            ac2 = ac2 * sc + ex * x2;
            ac3 = ac3 * sc + ex * x3;
            m = mn;
        }

        float inv = 1.f / den;
        half4v rh = *(const half4v*)(res16 + (size_t)n * 64 + c0);
        float h0, h1, h2, h3;
        if (bias) {
            const float4 b4 = *(const float4*)(bias + c0);
            h0 = relu(ac0 * inv + b4.x) + (float)rh.x;
            h1 = relu(ac1 * inv + b4.y) + (float)rh.y;
            h2 = relu(ac2 * inv + b4.z) + (float)rh.z;
            h3 = relu(ac3 * inv + b4.w) + (float)rh.w;
        } else {
            h0 = relu(ac0 * inv) + (float)rh.x;
            h1 = relu(ac1 * inv) + (float)rh.y;
            h2 = relu(ac2 * inv) + (float)rh.z;
            h3 = relu(ac3 * inv) + (float)rh.w;
        }

        if (!DEC) {
            if (nvalid) {
                float4 o; o.x = h0; o.y = h1; o.z = h2; o.w = h3;
                *(float4*)(hout + (size_t)n * 64 + c0) = o;
            }
        } else {
            float p0 = h0 * wcomb[(c0 + 0) * 2] + h1 * wcomb[(c0 + 1) * 2]
                     + h2 * wcomb[(c0 + 2) * 2] + h3 * wcomb[(c0 + 3) * 2];
            float p1 = h0 * wcomb[(c0 + 0) * 2 + 1] + h1 * wcomb[(c0 + 1) * 2 + 1]
                     + h2 * wcomb[(c0 + 2) * 2 + 1] + h3 * wcomb[(c0 + 3) * 2 + 1];
            if (q < 4) {
                float4 c4 = *(const float4*)(cond + (size_t)n * 16 + q * 4);
                int d0 = 80 + q * 4;
                p0 += c4.x * wcomb[(d0 + 0) * 2] + c4.y * wcomb[(d0 + 1) * 2]
                    + c4.z * wcomb[(d0 + 2) * 2] + c4.w * wcomb[(d0 + 3) * 2];
                p1 += c4.x * wcomb[(d0 + 0) * 2 + 1] + c4.y * wcomb[(d0 + 1) * 2 + 1]
                    + c4.z * wcomb[(d0 + 2) * 2 + 1] + c4.w * wcomb[(d0 + 3) * 2 + 1];
            }
            #pragma unroll
            for (int off = 1; off < 16; off <<= 1) {
                p0 += __shfl_xor(p0, off, 16);
                p1 += __shfl_xor(p1, off, 16);
            }
            if (q == 0 && nvalid) {
                out[(size_t)n * 2] = p0 + bfinal[0];
                out[(size_t)n * 2 + 1] = p1 + bfinal[1];
            }
        }
    }
}

static inline int gblk(long long threads) { return (int)((threads + BLK - 1) / BLK); }

extern "C" void kernel_launch(void* const* d_in, const int* in_sizes, int n_in,
                              void* d_out, int out_size, void* d_ws, size_t ws_size,
                              hipStream_t stream) {
    const float* x     = (const float*)d_in[0];
    const int*   ei    = (const int*)d_in[1];
    const int*   t     = (const int*)d_in[2];
    const float* cond  = (const float*)d_in[3];
    const float* Wl0   = (const float*)d_in[4];
    const float* bl0   = (const float*)d_in[5];
    const float* Wr0   = (const float*)d_in[6];
    const float* br0   = (const float*)d_in[7];
    const float* att0  = (const float*)d_in[8];
    const float* bias0 = (const float*)d_in[9];
    const float* Wres0 = (const float*)d_in[10];
    const float* bres0 = (const float*)d_in[11];
    const float* Wl1   = (const float*)d_in[12];
    const float* Wr1   = (const float*)d_in[13];
    const float* att1  = (const float*)d_in[14];
    const float* Wres1 = (const float*)d_in[15];
    const float* bres1 = (const float*)d_in[16];
    const float* Wt0   = (const float*)d_in[17];
    const float* bt0   = (const float*)d_in[18];
    const float* Wt1   = (const float*)d_in[19];
    const float* bt1   = (const float*)d_in[20];
    const float* Wfd   = (const float*)d_in[21];
    const float* bfd   = (const float*)d_in[22];
    const float* Wcls  = (const float*)d_in[23];
    const float* bcls  = (const float*)d_in[24];
    float* out = (float*)d_out;

    const int N   = in_sizes[0] / 16;
    const int E   = in_sizes[1] / 2;
    const int NBC = (N + CDST - 1) / CDST;
    const int NBF = (N + BDST - 1) / BDST;

    float* ws = (float*)d_ws;
    size_t o = 0;
    float* hbuf  = ws + o; o += (size_t)N * 64;
    _Float16* xlh   = (_Float16*)(ws + o); o += (size_t)N * 32;  // 16B-aligned
    _Float16* xr16  = (_Float16*)(ws + o); o += (size_t)N * 32;
    _Float16* res16 = (_Float16*)(ws + o); o += (size_t)N * 32;
    float* wcomb = ws + o; o += 192;
    float* bfin  = ws + o; o += 2;
    int* iws     = (int*)(ws + o);
    size_t io = 0;
    int* ccnt  = iws + io; io += NBC_MAX;
    int* cbase = iws + io; io += NBC_MAX + 1;
    int* ccur  = iws + io; io += NBC_MAX;
    int* fbeg  = iws + io; io += NBF;
    int* fend  = iws + io; io += NBF;
    int* part  = iws + io; io += E;
    int* srcs  = iws + io; io += E;

    const int partBlocks = (E + CHUNK - 1) / CHUNK;

    // tiny decoder/time precompute
    k_tiny<<<1, BLK, 0, stream>>>(t, Wt0, bt0, Wt1, bt1, Wfd, bfd, Wcls, bcls, wcomb, bfin);

    // ---- radix partition by destination ----
    k_zeroc<<<gblk(NBC), BLK, 0, stream>>>(ccnt, NBC);
    k_histc<<<partBlocks, BLK, 0, stream>>>(ei, E, NBC, ccnt);
    k_scan<<<1, BLK, 0, stream>>>(ccnt, NBC, E, cbase, ccur);
    k_part<<<partBlocks, BLK, 0, stream>>>(ei, E, NBC, ccur, part);
    k_refine<<<NBC, BLK, 0, stream>>>(cbase, part, NBF, fbeg, fend, srcs);

    // ---- layer 0 ----
    k_pre0f<<<gblk((long long)((N + 3) / 4) * 64), BLK, 0, stream>>>(
        x, Wl0, bl0, Wr0, br0, Wres0, bres0, xlh, xr16, res16, N);
    k_gat3<false><<<NBF, BLK, 0, stream>>>(fbeg, fend, srcs, xlh, xr16, att0, bias0, res16,
                                           hbuf, nullptr, nullptr, nullptr, nullptr, N);

    // ---- layer 1 (decoder fused) ----
    k_pre1w<<<(N + 31) / 32, BLK, 0, stream>>>(hbuf, Wl1, Wr1, Wres1, bres1, xlh, xr16, res16, N);
    k_gat3<true><<<NBF, BLK, 0, stream>>>(fbeg, fend, srcs, xlh, xr16, att1, nullptr, res16,
                                          nullptr, cond, wcomb, bfin, out, N);
}

// Round 10
// 319.307 us; speedup vs baseline: 1.4601x; 1.0864x over previous
//
#include <hip/hip_runtime.h>
#include <hip/hip_bf16.h>
#include <hip/hip_fp16.h>
#include <math.h>

// Edge_Encoder_Residual: 2-layer GATv2 on line-graph + time-MLP + decoder.
// Round 10: gat3 edge loop processes 2 edges/iteration with a combined
// online-softmax update (halves the serial fmax/exp/acc dependency chain,
// doubles gather ILP). hbuf stored fp16 (gat3<0> -> pre1w boundary).
// Base structure = r9 (radix partition + slim fp16 pre + fused decoder).

#define BLK 256
#define BDST 32            // dsts per fine bucket
#define CDST 256           // dsts per coarse bucket
#define CHUNK 4096         // edges per k_part block
#define FCAP 768           // tag capacity per fine bucket (mean 512)
#define NBC_MAX 512

typedef _Float16 half4v __attribute__((ext_vector_type(4)));
typedef _Float16 half2v __attribute__((ext_vector_type(2)));

__device__ __forceinline__ float leaky02(float x) { return x >= 0.f ? x : 0.2f * x; }
__device__ __forceinline__ float relu(float x) { return x > 0.f ? x : 0.f; }

// ---------- tiny: time embedding + MLP + collapsed decoder matrices ----------
__global__ void k_tiny(const int* __restrict__ t,
                       const float* __restrict__ Wt0, const float* __restrict__ bt0,
                       const float* __restrict__ Wt1, const float* __restrict__ bt1,
                       const float* __restrict__ Wfd, const float* __restrict__ bfd,
                       const float* __restrict__ Wcls, const float* __restrict__ bcls,
                       float* __restrict__ wcomb,   // [96][2]
                       float* __restrict__ bfinal)  // [2]
{
    __shared__ float temb[16];
    int tid = threadIdx.x;
    if (tid == 0) {
        float tf = (float)t[0];
        float e0[16], v1[16];
        const float cexp = -logf(10000.f) / 7.f;
        for (int j = 0; j < 8; ++j) {
            float ang = tf * expf((float)j * cexp);
            e0[j] = sinf(ang);
            e0[8 + j] = cosf(ang);
        }
        for (int i = 0; i < 16; ++i) {
            float a = bt0[i];
            for (int j = 0; j < 16; ++j) a += e0[j] * Wt0[j * 16 + i];
            v1[i] = a / (1.f + expf(-a));
        }
        for (int i = 0; i < 16; ++i) {
            float a = bt1[i];
            for (int j = 0; j < 16; ++j) a += v1[j] * Wt1[j * 16 + i];
            temb[i] = a / (1.f + expf(-a));
        }
    }
    __syncthreads();
    if (tid < 192) {
        int i = tid >> 1, k = tid & 1;
        float a = 0.f;
        for (int j = 0; j < 32; ++j) a += Wfd[i * 32 + j] * Wcls[j * 2 + k];
        wcomb[tid] = a;
    }
    __syncthreads();
    if (tid < 2) {
        float a = bcls[tid];
        for (int j = 0; j < 32; ++j) a += bfd[j] * Wcls[j * 2 + tid];
        for (int d = 0; d < 16; ++d) a += temb[d] * wcomb[(64 + d) * 2 + tid];
        bfinal[tid] = a;
    }
}

// ---------- radix pipeline (unchanged since round 6) ----------
__global__ void k_zeroc(int* __restrict__ ccnt, int NBC)
{
    int gid = blockIdx.x * BLK + threadIdx.x;
    if (gid < NBC) ccnt[gid] = 0;
}

__global__ void k_histc(const int* __restrict__ ei, int E, int NBC,
                        int* __restrict__ ccnt)
{
    __shared__ int h[NBC_MAX];
    int tid = threadIdx.x;
    for (int i = tid; i < NBC; i += BLK) h[i] = 0;
    __syncthreads();
    int e0 = blockIdx.x * CHUNK;
    #pragma unroll
    for (int k = 0; k < CHUNK / BLK; ++k) {
        int e = e0 + tid + k * BLK;
        if (e < E) atomicAdd(&h[ei[E + e] >> 8], 1);
    }
    __syncthreads();
    for (int i = tid; i < NBC; i += BLK) {
        int v = h[i];
        if (v) atomicAdd(&ccnt[i], v);   // fire-and-forget -> pipelines
    }
}

__global__ void k_scan(const int* __restrict__ ccnt, int NBC, int E,
                       int* __restrict__ cbase, int* __restrict__ ccur)
{
    if (threadIdx.x == 0) {
        int acc = 0;
        for (int i = 0; i < NBC; ++i) {
            cbase[i] = acc;
            acc += ccnt[i];
        }
        cbase[NBC] = acc;
    }
    __syncthreads();
    for (int i = threadIdx.x; i < NBC; i += BLK) ccur[i] = cbase[i];
}

__global__ void k_part(const int* __restrict__ ei, int E, int NBC,
                       int* __restrict__ ccur, int* __restrict__ part)
{
    __shared__ int h[NBC_MAX];
    __shared__ int gb[NBC_MAX];
    int tid = threadIdx.x;
    int e0 = blockIdx.x * CHUNK;
    for (int i = tid; i < NBC; i += BLK) h[i] = 0;
    __syncthreads();
    int sv[CHUNK / BLK], dv[CHUNK / BLK];
    #pragma unroll
    for (int k = 0; k < CHUNK / BLK; ++k) {
        int e = e0 + tid + k * BLK;
        if (e < E) {
            sv[k] = ei[e];
            dv[k] = ei[E + e];
            atomicAdd(&h[dv[k] >> 8], 1);
        } else dv[k] = -1;
    }
    __syncthreads();
    for (int i = tid; i < NBC; i += BLK) {
        int v = h[i];
        gb[i] = v ? atomicAdd(&ccur[i], v) : 0;   // block-agg returning atomics
    }
    __syncthreads();
    for (int i = tid; i < NBC; i += BLK) h[i] = gb[i];
    __syncthreads();
    #pragma unroll
    for (int k = 0; k < CHUNK / BLK; ++k) {
        if (dv[k] >= 0) {
            int p = atomicAdd(&h[dv[k] >> 8], 1);   // LDS atomic
            part[p] = (sv[k] << 8) | (dv[k] & 255);
        }
    }
}

__global__ void k_refine(const int* __restrict__ cbase, const int* __restrict__ part,
                         int NBF, int* __restrict__ fbeg, int* __restrict__ fend,
                         int* __restrict__ srcs)
{
    __shared__ int fcnt[8];
    __shared__ int fcur[8];
    int b = blockIdx.x, tid = threadIdx.x;
    int beg = cbase[b], end = cbase[b + 1];
    if (tid < 8) fcnt[tid] = 0;
    __syncthreads();
    for (int k = beg + tid; k < end; k += BLK)
        atomicAdd(&fcnt[(part[k] >> 5) & 7], 1);
    __syncthreads();
    if (tid == 0) {
        int acc = beg;
        #pragma unroll
        for (int f = 0; f < 8; ++f) {
            int fb = b * 8 + f;
            fcur[f] = acc;
            if (fb < NBF) { fbeg[fb] = acc; acc += fcnt[f]; fend[fb] = acc; }
        }
    }
    __syncthreads();
    for (int k = beg + tid; k < end; k += BLK) {
        int tg = part[k];
        int p = atomicAdd(&fcur[(tg >> 5) & 7], 1);
        srcs[p] = ((tg >> 8) << 5) | (tg & 31);
    }
}

// ---------- layer 0 precompute: xl, xr, res — all fp16, 4 nodes/wave ----------
__global__ void k_pre0f(const float* __restrict__ x,
                        const float* __restrict__ Wl, const float* __restrict__ bl,
                        const float* __restrict__ Wr, const float* __restrict__ br,
                        const float* __restrict__ Wres, const float* __restrict__ bres,
                        _Float16* __restrict__ xlh, _Float16* __restrict__ xr16,
                        _Float16* __restrict__ res16, int N)
{
    int wid = (int)(((long long)blockIdx.x * BLK + threadIdx.x) >> 6);
    int lane = threadIdx.x & 63;
    int g = lane >> 4, q = lane & 15;
    int n = wid * 4 + g;
    bool valid = n < N;
    int nn = valid ? n : N - 1;
    float xv = x[(size_t)nn * 16 + q];
    int c0 = q * 4;
    float4 accl = *(const float4*)(bl + c0);
    float4 accr = *(const float4*)(br + c0);
    float4 accs = *(const float4*)(bres + c0);
    #pragma unroll
    for (int k = 0; k < 16; ++k) {
        float xk = __shfl(xv, (g << 4) | k, 64);
        float4 wl = *(const float4*)(Wl + k * 64 + c0);
        float4 wr = *(const float4*)(Wr + k * 64 + c0);
        float4 wsv = *(const float4*)(Wres + k * 64 + c0);
        accl.x = fmaf(xk, wl.x, accl.x);
        accl.y = fmaf(xk, wl.y, accl.y);
        accl.z = fmaf(xk, wl.z, accl.z);
        accl.w = fmaf(xk, wl.w, accl.w);
        accr.x = fmaf(xk, wr.x, accr.x);
        accr.y = fmaf(xk, wr.y, accr.y);
        accr.z = fmaf(xk, wr.z, accr.z);
        accr.w = fmaf(xk, wr.w, accr.w);
        accs.x = fmaf(xk, wsv.x, accs.x);
        accs.y = fmaf(xk, wsv.y, accs.y);
        accs.z = fmaf(xk, wsv.z, accs.z);
        accs.w = fmaf(xk, wsv.w, accs.w);
    }
    if (valid) {
        size_t base = (size_t)n * 64 + c0;
        half4v hl, hr, hs;
        hl.x = (_Float16)accl.x; hl.y = (_Float16)accl.y;
        hl.z = (_Float16)accl.z; hl.w = (_Float16)accl.w;
        hr.x = (_Float16)accr.x; hr.y = (_Float16)accr.y;
        hr.z = (_Float16)accr.z; hr.w = (_Float16)accr.w;
        hs.x = (_Float16)relu(accs.x); hs.y = (_Float16)relu(accs.y);
        hs.z = (_Float16)relu(accs.z); hs.w = (_Float16)relu(accs.w);
        *(half4v*)(xlh + base) = hl;
        *(half4v*)(xr16 + base) = hr;
        *(half4v*)(res16 + base) = hs;
    }
}

// ---------- layer 1 precompute: LDS-staged fp16 W + fp16 h input ----------
__global__ void k_pre1w(const _Float16* __restrict__ h16,
                        const float* __restrict__ Wl, const float* __restrict__ Wr,
                        const float* __restrict__ Wres, const float* __restrict__ bres,
                        _Float16* __restrict__ xlh, _Float16* __restrict__ xr16,
                        _Float16* __restrict__ res16, int N)
{
    __shared__ _Float16 wlds[32][3][64][2];
    __shared__ float hlds[32][64];
    int tid = threadIdx.x;
    int nb = blockIdx.x * 32;

    for (int idx = tid; idx < 3 * 4096; idx += BLK) {
        int m = idx >> 12, rem = idx & 4095;
        int k = rem >> 6, c = rem & 63;
        const float* W = (m == 0) ? Wl : (m == 1) ? Wr : Wres;
        wlds[k >> 1][m][c][k & 1] = (_Float16)W[k * 64 + c];
    }
    for (int idx = tid; idx < 512; idx += BLK) {   // 512 half4s = 32*64 halves
        int i = idx >> 4, c4 = idx & 15;
        int n = nb + i; if (n >= N) n = N - 1;
        half4v hv = *(const half4v*)(h16 + (size_t)n * 64 + c4 * 4);
        hlds[i][c4 * 4 + 0] = (float)hv.x;
        hlds[i][c4 * 4 + 1] = (float)hv.y;
        hlds[i][c4 * 4 + 2] = (float)hv.z;
        hlds[i][c4 * 4 + 3] = (float)hv.w;
    }
    __syncthreads();

    int c = tid & 63, w = tid >> 6;
    float al[8], ar[8], as[8];
    float vbs = bres[c];
    #pragma unroll
    for (int i = 0; i < 8; ++i) { al[i] = 0.f; ar[i] = 0.f; as[i] = vbs; }

    #pragma unroll 4
    for (int k4 = 0; k4 < 16; ++k4) {
        half2v wlA = *(const half2v*)&wlds[2 * k4][0][c][0];
        half2v wrA = *(const half2v*)&wlds[2 * k4][1][c][0];
        half2v wsA = *(const half2v*)&wlds[2 * k4][2][c][0];
        half2v wlB = *(const half2v*)&wlds[2 * k4 + 1][0][c][0];
        half2v wrB = *(const half2v*)&wlds[2 * k4 + 1][1][c][0];
        half2v wsB = *(const half2v*)&wlds[2 * k4 + 1][2][c][0];
        float l0 = (float)wlA.x, l1 = (float)wlA.y, l2 = (float)wlB.x, l3 = (float)wlB.y;
        float r0 = (float)wrA.x, r1 = (float)wrA.y, r2 = (float)wrB.x, r3 = (float)wrB.y;
        float s0 = (float)wsA.x, s1 = (float)wsA.y, s2 = (float)wsB.x, s3 = (float)wsB.y;
        #pragma unroll
        for (int i = 0; i < 8; ++i) {
            float4 hv = *(const float4*)&hlds[w * 8 + i][4 * k4];   // broadcast
            al[i] += hv.x * l0 + hv.y * l1 + hv.z * l2 + hv.w * l3;
            ar[i] += hv.x * r0 + hv.y * r1 + hv.z * r2 + hv.w * r3;
            as[i] += hv.x * s0 + hv.y * s1 + hv.z * s2 + hv.w * s3;
        }
    }
    #pragma unroll
    for (int i = 0; i < 8; ++i) {
        int n = nb + w * 8 + i;
        if (n < N) {
            xlh[(size_t)n * 64 + c]   = (_Float16)al[i];
            xr16[(size_t)n * 64 + c]  = (_Float16)ar[i];
            res16[(size_t)n * 64 + c] = (_Float16)relu(as[i]);
        }
    }
}

// ---------- fused GATv2: 2-edge-batched online softmax ----------
template <bool DEC>
__global__ void k_gat3(const int* __restrict__ fbeg, const int* __restrict__ fend,
                       const int* __restrict__ srcs,
                       const _Float16* __restrict__ xlh, const _Float16* __restrict__ xr16,
                       const float* __restrict__ att, const float* __restrict__ bias,
                       const _Float16* __restrict__ res16,
                       _Float16* __restrict__ hout16,
                       const float* __restrict__ cond, const float* __restrict__ wcomb,
                       const float* __restrict__ bfinal, float* __restrict__ out,
                       int N)
{
    __shared__ int lh[BDST];
    __shared__ int rp[BDST + 1];
    __shared__ int cc[BDST];
    __shared__ int tags[FCAP];

    int b = blockIdx.x;
    int tid = threadIdx.x;
    int beg = fbeg[b];
    int nE = fend[b] - beg; if (nE > FCAP) nE = FCAP;

    if (tid < BDST) lh[tid] = 0;
    __syncthreads();
    for (int k = tid; k < nE; k += BLK) atomicAdd(&lh[srcs[beg + k] & 31], 1);
    __syncthreads();
    if (tid == 0) {
        int acc = 0;
        rp[0] = 0;
        #pragma unroll
        for (int i = 0; i < BDST; ++i) { acc += lh[i]; rp[i + 1] = acc; }
    }
    __syncthreads();
    if (tid < BDST) cc[tid] = rp[tid];
    __syncthreads();
    for (int k = tid; k < nE; k += BLK) {
        int tg = srcs[beg + k];
        int r = atomicAdd(&cc[tg & 31], 1);
        tags[r] = tg >> 5;
    }
    __syncthreads();

    int lane = tid & 63, w = tid >> 6;
    int g = lane >> 4, q = lane & 15;
    int c0 = q * 4;
    float4 a4 = *(const float4*)(att + c0);

    #pragma unroll
    for (int rep = 0; rep < 2; ++rep) {
        int dlow = w * 8 + rep * 4 + g;
        int node = b * BDST + dlow;
        bool nvalid = node < N;
        int n = nvalid ? node : 0;

        half4v xrh = *(const half4v*)(xr16 + (size_t)n * 64 + c0);
        float xrx = (float)xrh.x, xry = (float)xrh.y, xrz = (float)xrh.z, xrw = (float)xrh.w;

        half4v hs = *(const half4v*)(xlh + (size_t)n * 64 + c0);
        float s0 = (float)hs.x, s1 = (float)hs.y, s2 = (float)hs.z, s3 = (float)hs.w;
        float lv = leaky02(s0 + xrx) * a4.x + leaky02(s1 + xry) * a4.y
                 + leaky02(s2 + xrz) * a4.z + leaky02(s3 + xrw) * a4.w;
        lv += __shfl_xor(lv, 1, 8);
        lv += __shfl_xor(lv, 2, 8);
        lv += __shfl_xor(lv, 4, 8);

        float m = lv, den = 1.f;
        float ac0 = s0, ac1 = s1, ac2 = s2, ac3 = s3;

        int deg = nvalid ? (rp[dlow + 1] - rp[dlow]) : 0;
        int base = nvalid ? rp[dlow] : 0;

        int t1 = max(deg, __shfl_xor(deg, 16, 64));
        int wavemax = max(t1, __shfl_xor(t1, 32, 64));

        // 2-deep prefetch (pair)
        int i1 = (0 < deg) ? tags[base] : n;
        int i2 = (1 < deg) ? tags[base + 1] : n;
        half4v p1 = *(const half4v*)(xlh + (size_t)i1 * 64 + c0);
        half4v p2 = *(const half4v*)(xlh + (size_t)i2 * 64 + c0);

        for (int j = 0; j < wavemax; j += 2) {
            bool a1 = j < deg, a2 = j + 1 < deg;
            half4v h1 = p1, h2 = p2;
            int n1 = (j + 2 < deg) ? tags[base + j + 2] : n;
            int n2 = (j + 3 < deg) ? tags[base + j + 3] : n;
            p1 = *(const half4v*)(xlh + (size_t)n1 * 64 + c0);
            p2 = *(const half4v*)(xlh + (size_t)n2 * 64 + c0);

            float x10 = (float)h1.x, x11 = (float)h1.y, x12 = (float)h1.z, x13 = (float)h1.w;
            float x20 = (float)h2.x, x21 = (float)h2.y, x22 = (float)h2.z, x23 = (float)h2.w;
            float e1 = leaky02(x10 + xrx) * a4.x + leaky02(x11 + xry) * a4.y
                     + leaky02(x12 + xrz) * a4.z + leaky02(x13 + xrw) * a4.w;
            float e2 = leaky02(x20 + xrx) * a4.x + leaky02(x21 + xry) * a4.y
                     + leaky02(x22 + xrz) * a4.z + leaky02(x23 + xrw) * a4.w;
            e1 += __shfl_xor(e1, 1, 8);
            e2 += __shfl_xor(e2, 1, 8);
            e1 += __shfl_xor(e1, 2, 8);
            e2 += __shfl_xor(e2, 2, 8);
            e1 += __shfl_xor(e1, 4, 8);
            e2 += __shfl_xor(e2, 4, 8);
            if (!a1) e1 = -1e30f;
            if (!a2) e2 = -1e30f;

            float mn = fmaxf(m, fmaxf(e1, e2));
            float sc  = __expf(m - mn);
            float ex1 = __expf(e1 - mn);
            float ex2 = __expf(e2 - mn);
            den = den * sc + ex1 + ex2;
            ac0 = ac0 * sc + ex1 * x10 + ex2 * x20;
            ac1 = ac1 * sc + ex1 * x11 + ex2 * x21;
            ac2 = ac2 * sc + ex1 * x12 + ex2 * x22;
            ac3 = ac3 * sc + ex1 * x13 + ex2 * x23;
            m = mn;
        }

        float inv = 1.f / den;
        half4v rh = *(const half4v*)(res16 + (size_t)n * 64 + c0);
        float h0, h1, h2, h3;
        if (bias) {
            const float4 b4 = *(const float4*)(bias + c0);
            h0 = relu(ac0 * inv + b4.x) + (float)rh.x;
            h1 = relu(ac1 * inv + b4.y) + (float)rh.y;
            h2 = relu(ac2 * inv + b4.z) + (float)rh.z;
            h3 = relu(ac3 * inv + b4.w) + (float)rh.w;
        } else {
            h0 = relu(ac0 * inv) + (float)rh.x;
            h1 = relu(ac1 * inv) + (float)rh.y;
            h2 = relu(ac2 * inv) + (float)rh.z;
            h3 = relu(ac3 * inv) + (float)rh.w;
        }

        if (!DEC) {
            if (nvalid) {
                half4v o;
                o.x = (_Float16)h0; o.y = (_Float16)h1;
                o.z = (_Float16)h2; o.w = (_Float16)h3;
                *(half4v*)(hout16 + (size_t)n * 64 + c0) = o;
            }
        } else {
            float p0 = h0 * wcomb[(c0 + 0) * 2] + h1 * wcomb[(c0 + 1) * 2]
                     + h2 * wcomb[(c0 + 2) * 2] + h3 * wcomb[(c0 + 3) * 2];
            float p1d = h0 * wcomb[(c0 + 0) * 2 + 1] + h1 * wcomb[(c0 + 1) * 2 + 1]
                      + h2 * wcomb[(c0 + 2) * 2 + 1] + h3 * wcomb[(c0 + 3) * 2 + 1];
            if (q < 4) {
                float4 c4 = *(const float4*)(cond + (size_t)n * 16 + q * 4);
                int d0 = 80 + q * 4;
                p0 += c4.x * wcomb[(d0 + 0) * 2] + c4.y * wcomb[(d0 + 1) * 2]
                    + c4.z * wcomb[(d0 + 2) * 2] + c4.w * wcomb[(d0 + 3) * 2];
                p1d += c4.x * wcomb[(d0 + 0) * 2 + 1] + c4.y * wcomb[(d0 + 1) * 2 + 1]
                     + c4.z * wcomb[(d0 + 2) * 2 + 1] + c4.w * wcomb[(d0 + 3) * 2 + 1];
            }
            #pragma unroll
            for (int off = 1; off < 16; off <<= 1) {
                p0 += __shfl_xor(p0, off, 16);
                p1d += __shfl_xor(p1d, off, 16);
            }
            if (q == 0 && nvalid) {
                out[(size_t)n * 2] = p0 + bfinal[0];
                out[(size_t)n * 2 + 1] = p1d + bfinal[1];
            }
        }
    }
}

static inline int gblk(long long threads) { return (int)((threads + BLK - 1) / BLK); }

extern "C" void kernel_launch(void* const* d_in, const int* in_sizes, int n_in,
                              void* d_out, int out_size, void* d_ws, size_t ws_size,
                              hipStream_t stream) {
    const float* x     = (const float*)d_in[0];
    const int*   ei    = (const int*)d_in[1];
    const int*   t     = (const int*)d_in[2];
    const float* cond  = (const float*)d_in[3];
    const float* Wl0   = (const float*)d_in[4];
    const float* bl0   = (const float*)d_in[5];
    const float* Wr0   = (const float*)d_in[6];
    const float* br0   = (const float*)d_in[7];
    const float* att0  = (const float*)d_in[8];
    const float* bias0 = (const float*)d_in[9];
    const float* Wres0 = (const float*)d_in[10];
    const float* bres0 = (const float*)d_in[11];
    const float* Wl1   = (const float*)d_in[12];
    const float* Wr1   = (const float*)d_in[13];
    const float* att1  = (const float*)d_in[14];
    const float* Wres1 = (const float*)d_in[15];
    const float* bres1 = (const float*)d_in[16];
    const float* Wt0   = (const float*)d_in[17];
    const float* bt0   = (const float*)d_in[18];
    const float* Wt1   = (const float*)d_in[19];
    const float* bt1   = (const float*)d_in[20];
    const float* Wfd   = (const float*)d_in[21];
    const float* bfd   = (const float*)d_in[22];
    const float* Wcls  = (const float*)d_in[23];
    const float* bcls  = (const float*)d_in[24];
    float* out = (float*)d_out;

    const int N   = in_sizes[0] / 16;
    const int E   = in_sizes[1] / 2;
    const int NBC = (N + CDST - 1) / CDST;
    const int NBF = (N + BDST - 1) / BDST;

    float* ws = (float*)d_ws;
    size_t o = 0;
    _Float16* hbuf16 = (_Float16*)(ws + o); o += (size_t)N * 32;
    _Float16* xlh    = (_Float16*)(ws + o); o += (size_t)N * 32;
    _Float16* xr16   = (_Float16*)(ws + o); o += (size_t)N * 32;
    _Float16* res16  = (_Float16*)(ws + o); o += (size_t)N * 32;
    float* wcomb = ws + o; o += 192;
    float* bfin  = ws + o; o += 2;
    int* iws     = (int*)(ws + o);
    size_t io = 0;
    int* ccnt  = iws + io; io += NBC_MAX;
    int* cbase = iws + io; io += NBC_MAX + 1;
    int* ccur  = iws + io; io += NBC_MAX;
    int* fbeg  = iws + io; io += NBF;
    int* fend  = iws + io; io += NBF;
    int* part  = iws + io; io += E;
    int* srcs  = iws + io; io += E;

    const int partBlocks = (E + CHUNK - 1) / CHUNK;

    // tiny decoder/time precompute
    k_tiny<<<1, BLK, 0, stream>>>(t, Wt0, bt0, Wt1, bt1, Wfd, bfd, Wcls, bcls, wcomb, bfin);

    // ---- radix partition by destination ----
    k_zeroc<<<gblk(NBC), BLK, 0, stream>>>(ccnt, NBC);
    k_histc<<<partBlocks, BLK, 0, stream>>>(ei, E, NBC, ccnt);
    k_scan<<<1, BLK, 0, stream>>>(ccnt, NBC, E, cbase, ccur);
    k_part<<<partBlocks, BLK, 0, stream>>>(ei, E, NBC, ccur, part);
    k_refine<<<NBC, BLK, 0, stream>>>(cbase, part, NBF, fbeg, fend, srcs);

    // ---- layer 0 ----
    k_pre0f<<<gblk((long long)((N + 3) / 4) * 64), BLK, 0, stream>>>(
        x, Wl0, bl0, Wr0, br0, Wres0, bres0, xlh, xr16, res16, N);
    k_gat3<false><<<NBF, BLK, 0, stream>>>(fbeg, fend, srcs, xlh, xr16, att0, bias0, res16,
                                           hbuf16, nullptr, nullptr, nullptr, nullptr, N);

    // ---- layer 1 (decoder fused) ----
    k_pre1w<<<(N + 31) / 32, BLK, 0, stream>>>(hbuf16, Wl1, Wr1, Wres1, bres1, xlh, xr16, res16, N);
    k_gat3<true><<<NBF, BLK, 0, stream>>>(fbeg, fend, srcs, xlh, xr16, att1, nullptr, res16,
                                          nullptr, cond, wcomb, bfin, out, N);
}

// Round 11
// 293.561 us; speedup vs baseline: 1.5881x; 1.0877x over previous
//
#include <hip/hip_runtime.h>
#include <hip/hip_bf16.h>
#include <hip/hip_fp16.h>
#include <math.h>

// Edge_Encoder_Residual: 2-layer GATv2 on line-graph + time-MLP + decoder.
// Round 11: k_pre1w rewritten around v_dot2_f32_f16 (packed fp16 dot with
// f32 accumulate): 768 fdot2 replace 1536 scalar FMA + 192 cvt per thread
// (r10 counter audit: VALUBusy 80%, issue-bound). W staged as half4 k-pair
// tiles; h staged fp16 verbatim (zero conversions). Rest = r10 structure.

#define BLK 256
#define BDST 32            // dsts per fine bucket
#define CDST 256           // dsts per coarse bucket
#define CHUNK 4096         // edges per k_part block
#define FCAP 768           // tag capacity per fine bucket (mean 512)
#define NBC_MAX 512

typedef _Float16 half4v __attribute__((ext_vector_type(4)));
typedef _Float16 half2v __attribute__((ext_vector_type(2)));

#if __has_builtin(__builtin_amdgcn_fdot2)
#define FDOT2(a, b, c) __builtin_amdgcn_fdot2((a), (b), (c), false)
#else
__device__ __forceinline__ float fdot2_fallback(half2v a, half2v b, float c) {
    return c + (float)a.x * (float)b.x + (float)a.y * (float)b.y;
}
#define FDOT2(a, b, c) fdot2_fallback((a), (b), (c))
#endif

__device__ __forceinline__ float leaky02(float x) { return x >= 0.f ? x : 0.2f * x; }
__device__ __forceinline__ float relu(float x) { return x > 0.f ? x : 0.f; }

// ---------- tiny: time embedding + MLP + collapsed decoder matrices ----------
__global__ void k_tiny(const int* __restrict__ t,
                       const float* __restrict__ Wt0, const float* __restrict__ bt0,
                       const float* __restrict__ Wt1, const float* __restrict__ bt1,
                       const float* __restrict__ Wfd, const float* __restrict__ bfd,
                       const float* __restrict__ Wcls, const float* __restrict__ bcls,
                       float* __restrict__ wcomb,   // [96][2]
                       float* __restrict__ bfinal)  // [2]
{
    __shared__ float temb[16];
    int tid = threadIdx.x;
    if (tid == 0) {
        float tf = (float)t[0];
        float e0[16], v1[16];
        const float cexp = -logf(10000.f) / 7.f;
        for (int j = 0; j < 8; ++j) {
            float ang = tf * expf((float)j * cexp);
            e0[j] = sinf(ang);
            e0[8 + j] = cosf(ang);
        }
        for (int i = 0; i < 16; ++i) {
            float a = bt0[i];
            for (int j = 0; j < 16; ++j) a += e0[j] * Wt0[j * 16 + i];
            v1[i] = a / (1.f + expf(-a));
        }
        for (int i = 0; i < 16; ++i) {
            float a = bt1[i];
            for (int j = 0; j < 16; ++j) a += v1[j] * Wt1[j * 16 + i];
            temb[i] = a / (1.f + expf(-a));
        }
    }
    __syncthreads();
    if (tid < 192) {
        int i = tid >> 1, k = tid & 1;
        float a = 0.f;
        for (int j = 0; j < 32; ++j) a += Wfd[i * 32 + j] * Wcls[j * 2 + k];
        wcomb[tid] = a;
    }
    __syncthreads();
    if (tid < 2) {
        float a = bcls[tid];
        for (int j = 0; j < 32; ++j) a += bfd[j] * Wcls[j * 2 + tid];
        for (int d = 0; d < 16; ++d) a += temb[d] * wcomb[(64 + d) * 2 + tid];
        bfinal[tid] = a;
    }
}

// ---------- radix pipeline (unchanged since round 6) ----------
__global__ void k_zeroc(int* __restrict__ ccnt, int NBC)
{
    int gid = blockIdx.x * BLK + threadIdx.x;
    if (gid < NBC) ccnt[gid] = 0;
}

__global__ void k_histc(const int* __restrict__ ei, int E, int NBC,
                        int* __restrict__ ccnt)
{
    __shared__ int h[NBC_MAX];
    int tid = threadIdx.x;
    for (int i = tid; i < NBC; i += BLK) h[i] = 0;
    __syncthreads();
    int e0 = blockIdx.x * CHUNK;
    #pragma unroll
    for (int k = 0; k < CHUNK / BLK; ++k) {
        int e = e0 + tid + k * BLK;
        if (e < E) atomicAdd(&h[ei[E + e] >> 8], 1);
    }
    __syncthreads();
    for (int i = tid; i < NBC; i += BLK) {
        int v = h[i];
        if (v) atomicAdd(&ccnt[i], v);   // fire-and-forget -> pipelines
    }
}

__global__ void k_scan(const int* __restrict__ ccnt, int NBC, int E,
                       int* __restrict__ cbase, int* __restrict__ ccur)
{
    if (threadIdx.x == 0) {
        int acc = 0;
        for (int i = 0; i < NBC; ++i) {
            cbase[i] = acc;
            acc += ccnt[i];
        }
        cbase[NBC] = acc;
    }
    __syncthreads();
    for (int i = threadIdx.x; i < NBC; i += BLK) ccur[i] = cbase[i];
}

__global__ void k_part(const int* __restrict__ ei, int E, int NBC,
                       int* __restrict__ ccur, int* __restrict__ part)
{
    __shared__ int h[NBC_MAX];
    __shared__ int gb[NBC_MAX];
    int tid = threadIdx.x;
    int e0 = blockIdx.x * CHUNK;
    for (int i = tid; i < NBC; i += BLK) h[i] = 0;
    __syncthreads();
    int sv[CHUNK / BLK], dv[CHUNK / BLK];
    #pragma unroll
    for (int k = 0; k < CHUNK / BLK; ++k) {
        int e = e0 + tid + k * BLK;
        if (e < E) {
            sv[k] = ei[e];
            dv[k] = ei[E + e];
            atomicAdd(&h[dv[k] >> 8], 1);
        } else dv[k] = -1;
    }
    __syncthreads();
    for (int i = tid; i < NBC; i += BLK) {
        int v = h[i];
        gb[i] = v ? atomicAdd(&ccur[i], v) : 0;   // block-agg returning atomics
    }
    __syncthreads();
    for (int i = tid; i < NBC; i += BLK) h[i] = gb[i];
    __syncthreads();
    #pragma unroll
    for (int k = 0; k < CHUNK / BLK; ++k) {
        if (dv[k] >= 0) {
            int p = atomicAdd(&h[dv[k] >> 8], 1);   // LDS atomic
            part[p] = (sv[k] << 8) | (dv[k] & 255);
        }
    }
}

__global__ void k_refine(const int* __restrict__ cbase, const int* __restrict__ part,
                         int NBF, int* __restrict__ fbeg, int* __restrict__ fend,
                         int* __restrict__ srcs)
{
    __shared__ int fcnt[8];
    __shared__ int fcur[8];
    int b = blockIdx.x, tid = threadIdx.x;
    int beg = cbase[b], end = cbase[b + 1];
    if (tid < 8) fcnt[tid] = 0;
    __syncthreads();
    for (int k = beg + tid; k < end; k += BLK)
        atomicAdd(&fcnt[(part[k] >> 5) & 7], 1);
    __syncthreads();
    if (tid == 0) {
        int acc = beg;
        #pragma unroll
        for (int f = 0; f < 8; ++f) {
            int fb = b * 8 + f;
            fcur[f] = acc;
            if (fb < NBF) { fbeg[fb] = acc; acc += fcnt[f]; fend[fb] = acc; }
        }
    }
    __syncthreads();
    for (int k = beg + tid; k < end; k += BLK) {
        int tg = part[k];
        int p = atomicAdd(&fcur[(tg >> 5) & 7], 1);
        srcs[p] = ((tg >> 8) << 5) | (tg & 31);
    }
}

// ---------- layer 0 precompute: xl, xr, res — all fp16, 4 nodes/wave ----------
__global__ void k_pre0f(const float* __restrict__ x,
                        const float* __restrict__ Wl, const float* __restrict__ bl,
                        const float* __restrict__ Wr, const float* __restrict__ br,
                        const float* __restrict__ Wres, const float* __restrict__ bres,
                        _Float16* __restrict__ xlh, _Float16* __restrict__ xr16,
                        _Float16* __restrict__ res16, int N)
{
    int wid = (int)(((long long)blockIdx.x * BLK + threadIdx.x) >> 6);
    int lane = threadIdx.x & 63;
    int g = lane >> 4, q = lane & 15;
    int n = wid * 4 + g;
    bool valid = n < N;
    int nn = valid ? n : N - 1;
    float xv = x[(size_t)nn * 16 + q];
    int c0 = q * 4;
    float4 accl = *(const float4*)(bl + c0);
    float4 accr = *(const float4*)(br + c0);
    float4 accs = *(const float4*)(bres + c0);
    #pragma unroll
    for (int k = 0; k < 16; ++k) {
        float xk = __shfl(xv, (g << 4) | k, 64);
        float4 wl = *(const float4*)(Wl + k * 64 + c0);
        float4 wr = *(const float4*)(Wr + k * 64 + c0);
        float4 wsv = *(const float4*)(Wres + k * 64 + c0);
        accl.x = fmaf(xk, wl.x, accl.x);
        accl.y = fmaf(xk, wl.y, accl.y);
        accl.z = fmaf(xk, wl.z, accl.z);
        accl.w = fmaf(xk, wl.w, accl.w);
        accr.x = fmaf(xk, wr.x, accr.x);
        accr.y = fmaf(xk, wr.y, accr.y);
        accr.z = fmaf(xk, wr.z, accr.z);
        accr.w = fmaf(xk, wr.w, accr.w);
        accs.x = fmaf(xk, wsv.x, accs.x);
        accs.y = fmaf(xk, wsv.y, accs.y);
        accs.z = fmaf(xk, wsv.z, accs.z);
        accs.w = fmaf(xk, wsv.w, accs.w);
    }
    if (valid) {
        size_t base = (size_t)n * 64 + c0;
        half4v hl, hr, hs;
        hl.x = (_Float16)accl.x; hl.y = (_Float16)accl.y;
        hl.z = (_Float16)accl.z; hl.w = (_Float16)accl.w;
        hr.x = (_Float16)accr.x; hr.y = (_Float16)accr.y;
        hr.z = (_Float16)accr.z; hr.w = (_Float16)accr.w;
        hs.x = (_Float16)relu(accs.x); hs.y = (_Float16)relu(accs.y);
        hs.z = (_Float16)relu(accs.z); hs.w = (_Float16)relu(accs.w);
        *(half4v*)(xlh + base) = hl;
        *(half4v*)(xr16 + base) = hr;
        *(half4v*)(res16 + base) = hs;
    }
}

// ---------- layer 1 precompute: fdot2 (packed fp16 MAC, f32 accum) ----------
// Block = 4 waves, 32 nodes. LDS: 3x W half4[16][64] (8KB each) + h half4
// [32][16] (4KB) = 28KB. Lane c = output channel; wave w -> nodes w*8..w*8+7.
__global__ void k_pre1w(const _Float16* __restrict__ h16,
                        const float* __restrict__ Wl, const float* __restrict__ Wr,
                        const float* __restrict__ Wres, const float* __restrict__ bres,
                        _Float16* __restrict__ xlh, _Float16* __restrict__ xr16,
                        _Float16* __restrict__ res16, int N)
{
    __shared__ half4v wl4[16][64];
    __shared__ half4v wr4[16][64];
    __shared__ half4v ws4[16][64];
    __shared__ half4v h4[32][16];
    int tid = threadIdx.x;
    int nb = blockIdx.x * 32;

    // stage W: idx -> (m, k4, c); 4 coalesced f32 loads per half4
    for (int idx = tid; idx < 3 * 1024; idx += BLK) {
        int m = idx >> 10, rem = idx & 1023;
        int k4 = rem >> 6, c = rem & 63;
        const float* W = (m == 0) ? Wl : (m == 1) ? Wr : Wres;
        half4v v;
        v.x = (_Float16)W[(4 * k4 + 0) * 64 + c];
        v.y = (_Float16)W[(4 * k4 + 1) * 64 + c];
        v.z = (_Float16)W[(4 * k4 + 2) * 64 + c];
        v.w = (_Float16)W[(4 * k4 + 3) * 64 + c];
        (m == 0 ? wl4 : m == 1 ? wr4 : ws4)[k4][c] = v;
    }
    // stage h verbatim (fp16 -> fp16, 8B coalesced)
    for (int idx = tid; idx < 512; idx += BLK) {
        int i = idx >> 4, k4 = idx & 15;
        int n = nb + i; if (n >= N) n = N - 1;
        h4[i][k4] = *(const half4v*)(h16 + (size_t)n * 64 + k4 * 4);
    }
    __syncthreads();

    int c = tid & 63, w = tid >> 6;
    float al[8], ar[8], as[8];
    float vbs = bres[c];
    #pragma unroll
    for (int i = 0; i < 8; ++i) { al[i] = 0.f; ar[i] = 0.f; as[i] = vbs; }

    #pragma unroll 4
    for (int k4 = 0; k4 < 16; ++k4) {
        half4v wl = wl4[k4][c];
        half4v wr = wr4[k4][c];
        half4v wsv = ws4[k4][c];
        half2v wll = { wl.x, wl.y },  wlh = { wl.z, wl.w };
        half2v wrl = { wr.x, wr.y },  wrh = { wr.z, wr.w };
        half2v wsl = { wsv.x, wsv.y }, wsh = { wsv.z, wsv.w };
        #pragma unroll
        for (int i = 0; i < 8; ++i) {
            half4v hv = h4[w * 8 + i][k4];   // same-addr broadcast across wave
            half2v hl = { hv.x, hv.y }, hh = { hv.z, hv.w };
            al[i] = FDOT2(hl, wll, al[i]);
            al[i] = FDOT2(hh, wlh, al[i]);
            ar[i] = FDOT2(hl, wrl, ar[i]);
            ar[i] = FDOT2(hh, wrh, ar[i]);
            as[i] = FDOT2(hl, wsl, as[i]);
            as[i] = FDOT2(hh, wsh, as[i]);
        }
    }
    #pragma unroll
    for (int i = 0; i < 8; ++i) {
        int n = nb + w * 8 + i;
        if (n < N) {
            xlh[(size_t)n * 64 + c]   = (_Float16)al[i];
            xr16[(size_t)n * 64 + c]  = (_Float16)ar[i];
            res16[(size_t)n * 64 + c] = (_Float16)relu(as[i]);
        }
    }
}

// ---------- fused GATv2: 2-edge-batched online softmax ----------
template <bool DEC>
__global__ void k_gat3(const int* __restrict__ fbeg, const int* __restrict__ fend,
                       const int* __restrict__ srcs,
                       const _Float16* __restrict__ xlh, const _Float16* __restrict__ xr16,
                       const float* __restrict__ att, const float* __restrict__ bias,
                       const _Float16* __restrict__ res16,
                       _Float16* __restrict__ hout16,
                       const float* __restrict__ cond, const float* __restrict__ wcomb,
                       const float* __restrict__ bfinal, float* __restrict__ out,
                       int N)
{
    __shared__ int lh[BDST];
    __shared__ int rp[BDST + 1];
    __shared__ int cc[BDST];
    __shared__ int tags[FCAP];

    int b = blockIdx.x;
    int tid = threadIdx.x;
    int beg = fbeg[b];
    int nE = fend[b] - beg; if (nE > FCAP) nE = FCAP;

    if (tid < BDST) lh[tid] = 0;
    __syncthreads();
    for (int k = tid; k < nE; k += BLK) atomicAdd(&lh[srcs[beg + k] & 31], 1);
    __syncthreads();
    if (tid == 0) {
        int acc = 0;
        rp[0] = 0;
        #pragma unroll
        for (int i = 0; i < BDST; ++i) { acc += lh[i]; rp[i + 1] = acc; }
    }
    __syncthreads();
    if (tid < BDST) cc[tid] = rp[tid];
    __syncthreads();
    for (int k = tid; k < nE; k += BLK) {
        int tg = srcs[beg + k];
        int r = atomicAdd(&cc[tg & 31], 1);
        tags[r] = tg >> 5;
    }
    __syncthreads();

    int lane = tid & 63, w = tid >> 6;
    int g = lane >> 4, q = lane & 15;
    int c0 = q * 4;
    float4 a4 = *(const float4*)(att + c0);

    #pragma unroll
    for (int rep = 0; rep < 2; ++rep) {
        int dlow = w * 8 + rep * 4 + g;
        int node = b * BDST + dlow;
        bool nvalid = node < N;
        int n = nvalid ? node : 0;

        half4v xrh = *(const half4v*)(xr16 + (size_t)n * 64 + c0);
        float xrx = (float)xrh.x, xry = (float)xrh.y, xrz = (float)xrh.z, xrw = (float)xrh.w;

        half4v hs = *(const half4v*)(xlh + (size_t)n * 64 + c0);
        float s0 = (float)hs.x, s1 = (float)hs.y, s2 = (float)hs.z, s3 = (float)hs.w;
        float lv = leaky02(s0 + xrx) * a4.x + leaky02(s1 + xry) * a4.y
                 + leaky02(s2 + xrz) * a4.z + leaky02(s3 + xrw) * a4.w;
        lv += __shfl_xor(lv, 1, 8);
        lv += __shfl_xor(lv, 2, 8);
        lv += __shfl_xor(lv, 4, 8);

        float m = lv, den = 1.f;
        float ac0 = s0, ac1 = s1, ac2 = s2, ac3 = s3;

        int deg = nvalid ? (rp[dlow + 1] - rp[dlow]) : 0;
        int base = nvalid ? rp[dlow] : 0;

        int t1 = max(deg, __shfl_xor(deg, 16, 64));
        int wavemax = max(t1, __shfl_xor(t1, 32, 64));

        // 2-deep prefetch (pair)
        int i1 = (0 < deg) ? tags[base] : n;
        int i2 = (1 < deg) ? tags[base + 1] : n;
        half4v p1 = *(const half4v*)(xlh + (size_t)i1 * 64 + c0);
        half4v p2 = *(const half4v*)(xlh + (size_t)i2 * 64 + c0);

        for (int j = 0; j < wavemax; j += 2) {
            bool a1 = j < deg, a2 = j + 1 < deg;
            half4v h1 = p1, h2 = p2;
            int n1 = (j + 2 < deg) ? tags[base + j + 2] : n;
            int n2 = (j + 3 < deg) ? tags[base + j + 3] : n;
            p1 = *(const half4v*)(xlh + (size_t)n1 * 64 + c0);
            p2 = *(const half4v*)(xlh + (size_t)n2 * 64 + c0);

            float x10 = (float)h1.x, x11 = (float)h1.y, x12 = (float)h1.z, x13 = (float)h1.w;
            float x20 = (float)h2.x, x21 = (float)h2.y, x22 = (float)h2.z, x23 = (float)h2.w;
            float e1 = leaky02(x10 + xrx) * a4.x + leaky02(x11 + xry) * a4.y
                     + leaky02(x12 + xrz) * a4.z + leaky02(x13 + xrw) * a4.w;
            float e2 = leaky02(x20 + xrx) * a4.x + leaky02(x21 + xry) * a4.y
                     + leaky02(x22 + xrz) * a4.z + leaky02(x23 + xrw) * a4.w;
            e1 += __shfl_xor(e1, 1, 8);
            e2 += __shfl_xor(e2, 1, 8);
            e1 += __shfl_xor(e1, 2, 8);
            e2 += __shfl_xor(e2, 2, 8);
            e1 += __shfl_xor(e1, 4, 8);
            e2 += __shfl_xor(e2, 4, 8);
            if (!a1) e1 = -1e30f;
            if (!a2) e2 = -1e30f;

            float mn = fmaxf(m, fmaxf(e1, e2));
            float sc  = __expf(m - mn);
            float ex1 = __expf(e1 - mn);
            float ex2 = __expf(e2 - mn);
            den = den * sc + ex1 + ex2;
            ac0 = ac0 * sc + ex1 * x10 + ex2 * x20;
            ac1 = ac1 * sc + ex1 * x11 + ex2 * x21;
            ac2 = ac2 * sc + ex1 * x12 + ex2 * x22;
            ac3 = ac3 * sc + ex1 * x13 + ex2 * x23;
            m = mn;
        }

        float inv = 1.f / den;
        half4v rh = *(const half4v*)(res16 + (size_t)n * 64 + c0);
        float h0, h1, h2, h3;
        if (bias) {
            const float4 b4 = *(const float4*)(bias + c0);
            h0 = relu(ac0 * inv + b4.x) + (float)rh.x;
            h1 = relu(ac1 * inv + b4.y) + (float)rh.y;
            h2 = relu(ac2 * inv + b4.z) + (float)rh.z;
            h3 = relu(ac3 * inv + b4.w) + (float)rh.w;
        } else {
            h0 = relu(ac0 * inv) + (float)rh.x;
            h1 = relu(ac1 * inv) + (float)rh.y;
            h2 = relu(ac2 * inv) + (float)rh.z;
            h3 = relu(ac3 * inv) + (float)rh.w;
        }

        if (!DEC) {
            if (nvalid) {
                half4v o;
                o.x = (_Float16)h0; o.y = (_Float16)h1;
                o.z = (_Float16)h2; o.w = (_Float16)h3;
                *(half4v*)(hout16 + (size_t)n * 64 + c0) = o;
            }
        } else {
            float p0 = h0 * wcomb[(c0 + 0) * 2] + h1 * wcomb[(c0 + 1) * 2]
                     + h2 * wcomb[(c0 + 2) * 2] + h3 * wcomb[(c0 + 3) * 2];
            float p1d = h0 * wcomb[(c0 + 0) * 2 + 1] + h1 * wcomb[(c0 + 1) * 2 + 1]
                      + h2 * wcomb[(c0 + 2) * 2 + 1] + h3 * wcomb[(c0 + 3) * 2 + 1];
            if (q < 4) {
                float4 c4 = *(const float4*)(cond + (size_t)n * 16 + q * 4);
                int d0 = 80 + q * 4;
                p0 += c4.x * wcomb[(d0 + 0) * 2] + c4.y * wcomb[(d0 + 1) * 2]
                    + c4.z * wcomb[(d0 + 2) * 2] + c4.w * wcomb[(d0 + 3) * 2];
                p1d += c4.x * wcomb[(d0 + 0) * 2 + 1] + c4.y * wcomb[(d0 + 1) * 2 + 1]
                     + c4.z * wcomb[(d0 + 2) * 2 + 1] + c4.w * wcomb[(d0 + 3) * 2 + 1];
            }
            #pragma unroll
            for (int off = 1; off < 16; off <<= 1) {
                p0 += __shfl_xor(p0, off, 16);
                p1d += __shfl_xor(p1d, off, 16);
            }
            if (q == 0 && nvalid) {
                out[(size_t)n * 2] = p0 + bfinal[0];
                out[(size_t)n * 2 + 1] = p1d + bfinal[1];
            }
        }
    }
}

static inline int gblk(long long threads) { return (int)((threads + BLK - 1) / BLK); }

extern "C" void kernel_launch(void* const* d_in, const int* in_sizes, int n_in,
                              void* d_out, int out_size, void* d_ws, size_t ws_size,
                              hipStream_t stream) {
    const float* x     = (const float*)d_in[0];
    const int*   ei    = (const int*)d_in[1];
    const int*   t     = (const int*)d_in[2];
    const float* cond  = (const float*)d_in[3];
    const float* Wl0   = (const float*)d_in[4];
    const float* bl0   = (const float*)d_in[5];
    const float* Wr0   = (const float*)d_in[6];
    const float* br0   = (const float*)d_in[7];
    const float* att0  = (const float*)d_in[8];
    const float* bias0 = (const float*)d_in[9];
    const float* Wres0 = (const float*)d_in[10];
    const float* bres0 = (const float*)d_in[11];
    const float* Wl1   = (const float*)d_in[12];
    const float* Wr1   = (const float*)d_in[13];
    const float* att1  = (const float*)d_in[14];
    const float* Wres1 = (const float*)d_in[15];
    const float* bres1 = (const float*)d_in[16];
    const float* Wt0   = (const float*)d_in[17];
    const float* bt0   = (const float*)d_in[18];
    const float* Wt1   = (const float*)d_in[19];
    const float* bt1   = (const float*)d_in[20];
    const float* Wfd   = (const float*)d_in[21];
    const float* bfd   = (const float*)d_in[22];
    const float* Wcls  = (const float*)d_in[23];
    const float* bcls  = (const float*)d_in[24];
    float* out = (float*)d_out;

    const int N   = in_sizes[0] / 16;
    const int E   = in_sizes[1] / 2;
    const int NBC = (N + CDST - 1) / CDST;
    const int NBF = (N + BDST - 1) / BDST;

    float* ws = (float*)d_ws;
    size_t o = 0;
    _Float16* hbuf16 = (_Float16*)(ws + o); o += (size_t)N * 32;
    _Float16* xlh    = (_Float16*)(ws + o); o += (size_t)N * 32;
    _Float16* xr16   = (_Float16*)(ws + o); o += (size_t)N * 32;
    _Float16* res16  = (_Float16*)(ws + o); o += (size_t)N * 32;
    float* wcomb = ws + o; o += 192;
    float* bfin  = ws + o; o += 2;
    int* iws     = (int*)(ws + o);
    size_t io = 0;
    int* ccnt  = iws + io; io += NBC_MAX;
    int* cbase = iws + io; io += NBC_MAX + 1;
    int* ccur  = iws + io; io += NBC_MAX;
    int* fbeg  = iws + io; io += NBF;
    int* fend  = iws + io; io += NBF;
    int* part  = iws + io; io += E;
    int* srcs  = iws + io; io += E;

    const int partBlocks = (E + CHUNK - 1) / CHUNK;

    // tiny decoder/time precompute
    k_tiny<<<1, BLK, 0, stream>>>(t, Wt0, bt0, Wt1, bt1, Wfd, bfd, Wcls, bcls, wcomb, bfin);

    // ---- radix partition by destination ----
    k_zeroc<<<gblk(NBC), BLK, 0, stream>>>(ccnt, NBC);
    k_histc<<<partBlocks, BLK, 0, stream>>>(ei, E, NBC, ccnt);
    k_scan<<<1, BLK, 0, stream>>>(ccnt, NBC, E, cbase, ccur);
    k_part<<<partBlocks, BLK, 0, stream>>>(ei, E, NBC, ccur, part);
    k_refine<<<NBC, BLK, 0, stream>>>(cbase, part, NBF, fbeg, fend, srcs);

    // ---- layer 0 ----
    k_pre0f<<<gblk((long long)((N + 3) / 4) * 64), BLK, 0, stream>>>(
        x, Wl0, bl0, Wr0, br0, Wres0, bres0, xlh, xr16, res16, N);
    k_gat3<false><<<NBF, BLK, 0, stream>>>(fbeg, fend, srcs, xlh, xr16, att0, bias0, res16,
                                           hbuf16, nullptr, nullptr, nullptr, nullptr, N);

    // ---- layer 1 (decoder fused) ----
    k_pre1w<<<(N + 31) / 32, BLK, 0, stream>>>(hbuf16, Wl1, Wr1, Wres1, bres1, xlh, xr16, res16, N);
    k_gat3<true><<<NBF, BLK, 0, stream>>>(fbeg, fend, srcs, xlh, xr16, att1, nullptr, res16,
                                          nullptr, cond, wcomb, bfin, out, N);
}

// Round 12
// 274.439 us; speedup vs baseline: 1.6988x; 1.0697x over previous
//
#include <hip/hip_runtime.h>
#include <hip/hip_bf16.h>
#include <hip/hip_fp16.h>
#include <math.h>

// Edge_Encoder_Residual: 2-layer GATv2 on line-graph + time-MLP + decoder.
// Round 12: gat3 only — (1) degree-rank scheduling: the 32 dsts of a bucket
// are processed in degree-sorted order so each 4-dst wave group has similar
// degrees (kills the max-of-4 divergence, ~40% wasted iterations at
// Poisson(16)); (2) packed fp16 logit: pk_add/pk_max + v_dot2_f32_f16;
// (3) 4-edge batching with 4-deep gather prefetch. Rest = r11.

#define BLK 256
#define BDST 32            // dsts per fine bucket
#define CDST 256           // dsts per coarse bucket
#define CHUNK 4096         // edges per k_part block
#define FCAP 768           // tag capacity per fine bucket (mean 512)
#define NBC_MAX 512

typedef _Float16 half4v __attribute__((ext_vector_type(4)));
typedef _Float16 half2v __attribute__((ext_vector_type(2)));

#if __has_builtin(__builtin_amdgcn_fdot2)
#define FDOT2(a, b, c) __builtin_amdgcn_fdot2((a), (b), (c), false)
#else
__device__ __forceinline__ float fdot2_fallback(half2v a, half2v b, float c) {
    return c + (float)a.x * (float)b.x + (float)a.y * (float)b.y;
}
#define FDOT2(a, b, c) fdot2_fallback((a), (b), (c))
#endif

__device__ __forceinline__ float leaky02(float x) { return x >= 0.f ? x : 0.2f * x; }
__device__ __forceinline__ float relu(float x) { return x > 0.f ? x : 0.f; }

// packed logit partial: sum_c leaky(h[c]+xr[c])*att[c] over this lane's 4 ch
__device__ __forceinline__ float edot(half4v h, half2v xlo, half2v xhi,
                                      half2v alo, half2v ahi, half2v c02) {
    half2v lo = half2v{h.x, h.y} + xlo;
    half2v hi = half2v{h.z, h.w} + xhi;
    lo = __builtin_elementwise_max(lo, lo * c02);
    hi = __builtin_elementwise_max(hi, hi * c02);
    return FDOT2(lo, alo, FDOT2(hi, ahi, 0.f));
}

// ---------- tiny: time embedding + MLP + collapsed decoder matrices ----------
__global__ void k_tiny(const int* __restrict__ t,
                       const float* __restrict__ Wt0, const float* __restrict__ bt0,
                       const float* __restrict__ Wt1, const float* __restrict__ bt1,
                       const float* __restrict__ Wfd, const float* __restrict__ bfd,
                       const float* __restrict__ Wcls, const float* __restrict__ bcls,
                       float* __restrict__ wcomb,   // [96][2]
                       float* __restrict__ bfinal)  // [2]
{
    __shared__ float temb[16];
    int tid = threadIdx.x;
    if (tid == 0) {
        float tf = (float)t[0];
        float e0[16], v1[16];
        const float cexp = -logf(10000.f) / 7.f;
        for (int j = 0; j < 8; ++j) {
            float ang = tf * expf((float)j * cexp);
            e0[j] = sinf(ang);
            e0[8 + j] = cosf(ang);
        }
        for (int i = 0; i < 16; ++i) {
            float a = bt0[i];
            for (int j = 0; j < 16; ++j) a += e0[j] * Wt0[j * 16 + i];
            v1[i] = a / (1.f + expf(-a));
        }
        for (int i = 0; i < 16; ++i) {
            float a = bt1[i];
            for (int j = 0; j < 16; ++j) a += v1[j] * Wt1[j * 16 + i];
            temb[i] = a / (1.f + expf(-a));
        }
    }
    __syncthreads();
    if (tid < 192) {
        int i = tid >> 1, k = tid & 1;
        float a = 0.f;
        for (int j = 0; j < 32; ++j) a += Wfd[i * 32 + j] * Wcls[j * 2 + k];
        wcomb[tid] = a;
    }
    __syncthreads();
    if (tid < 2) {
        float a = bcls[tid];
        for (int j = 0; j < 32; ++j) a += bfd[j] * Wcls[j * 2 + tid];
        for (int d = 0; d < 16; ++d) a += temb[d] * wcomb[(64 + d) * 2 + tid];
        bfinal[tid] = a;
    }
}

// ---------- radix pipeline (unchanged since round 6) ----------
__global__ void k_zeroc(int* __restrict__ ccnt, int NBC)
{
    int gid = blockIdx.x * BLK + threadIdx.x;
    if (gid < NBC) ccnt[gid] = 0;
}

__global__ void k_histc(const int* __restrict__ ei, int E, int NBC,
                        int* __restrict__ ccnt)
{
    __shared__ int h[NBC_MAX];
    int tid = threadIdx.x;
    for (int i = tid; i < NBC; i += BLK) h[i] = 0;
    __syncthreads();
    int e0 = blockIdx.x * CHUNK;
    #pragma unroll
    for (int k = 0; k < CHUNK / BLK; ++k) {
        int e = e0 + tid + k * BLK;
        if (e < E) atomicAdd(&h[ei[E + e] >> 8], 1);
    }
    __syncthreads();
    for (int i = tid; i < NBC; i += BLK) {
        int v = h[i];
        if (v) atomicAdd(&ccnt[i], v);   // fire-and-forget -> pipelines
    }
}

__global__ void k_scan(const int* __restrict__ ccnt, int NBC, int E,
                       int* __restrict__ cbase, int* __restrict__ ccur)
{
    if (threadIdx.x == 0) {
        int acc = 0;
        for (int i = 0; i < NBC; ++i) {
            cbase[i] = acc;
            acc += ccnt[i];
        }
        cbase[NBC] = acc;
    }
    __syncthreads();
    for (int i = threadIdx.x; i < NBC; i += BLK) ccur[i] = cbase[i];
}

__global__ void k_part(const int* __restrict__ ei, int E, int NBC,
                       int* __restrict__ ccur, int* __restrict__ part)
{
    __shared__ int h[NBC_MAX];
    __shared__ int gb[NBC_MAX];
    int tid = threadIdx.x;
    int e0 = blockIdx.x * CHUNK;
    for (int i = tid; i < NBC; i += BLK) h[i] = 0;
    __syncthreads();
    int sv[CHUNK / BLK], dv[CHUNK / BLK];
    #pragma unroll
    for (int k = 0; k < CHUNK / BLK; ++k) {
        int e = e0 + tid + k * BLK;
        if (e < E) {
            sv[k] = ei[e];
            dv[k] = ei[E + e];
            atomicAdd(&h[dv[k] >> 8], 1);
        } else dv[k] = -1;
    }
    __syncthreads();
    for (int i = tid; i < NBC; i += BLK) {
        int v = h[i];
        gb[i] = v ? atomicAdd(&ccur[i], v) : 0;   // block-agg returning atomics
    }
    __syncthreads();
    for (int i = tid; i < NBC; i += BLK) h[i] = gb[i];
    __syncthreads();
    #pragma unroll
    for (int k = 0; k < CHUNK / BLK; ++k) {
        if (dv[k] >= 0) {
            int p = atomicAdd(&h[dv[k] >> 8], 1);   // LDS atomic
            part[p] = (sv[k] << 8) | (dv[k] & 255);
        }
    }
}

__global__ void k_refine(const int* __restrict__ cbase, const int* __restrict__ part,
                         int NBF, int* __restrict__ fbeg, int* __restrict__ fend,
                         int* __restrict__ srcs)
{
    __shared__ int fcnt[8];
    __shared__ int fcur[8];
    int b = blockIdx.x, tid = threadIdx.x;
    int beg = cbase[b], end = cbase[b + 1];
    if (tid < 8) fcnt[tid] = 0;
    __syncthreads();
    for (int k = beg + tid; k < end; k += BLK)
        atomicAdd(&fcnt[(part[k] >> 5) & 7], 1);
    __syncthreads();
    if (tid == 0) {
        int acc = beg;
        #pragma unroll
        for (int f = 0; f < 8; ++f) {
            int fb = b * 8 + f;
            fcur[f] = acc;
            if (fb < NBF) { fbeg[fb] = acc; acc += fcnt[f]; fend[fb] = acc; }
        }
    }
    __syncthreads();
    for (int k = beg + tid; k < end; k += BLK) {
        int tg = part[k];
        int p = atomicAdd(&fcur[(tg >> 5) & 7], 1);
        srcs[p] = ((tg >> 8) << 5) | (tg & 31);
    }
}

// ---------- layer 0 precompute: xl, xr, res — all fp16, 4 nodes/wave ----------
__global__ void k_pre0f(const float* __restrict__ x,
                        const float* __restrict__ Wl, const float* __restrict__ bl,
                        const float* __restrict__ Wr, const float* __restrict__ br,
                        const float* __restrict__ Wres, const float* __restrict__ bres,
                        _Float16* __restrict__ xlh, _Float16* __restrict__ xr16,
                        _Float16* __restrict__ res16, int N)
{
    int wid = (int)(((long long)blockIdx.x * BLK + threadIdx.x) >> 6);
    int lane = threadIdx.x & 63;
    int g = lane >> 4, q = lane & 15;
    int n = wid * 4 + g;
    bool valid = n < N;
    int nn = valid ? n : N - 1;
    float xv = x[(size_t)nn * 16 + q];
    int c0 = q * 4;
    float4 accl = *(const float4*)(bl + c0);
    float4 accr = *(const float4*)(br + c0);
    float4 accs = *(const float4*)(bres + c0);
    #pragma unroll
    for (int k = 0; k < 16; ++k) {
        float xk = __shfl(xv, (g << 4) | k, 64);
        float4 wl = *(const float4*)(Wl + k * 64 + c0);
        float4 wr = *(const float4*)(Wr + k * 64 + c0);
        float4 wsv = *(const float4*)(Wres + k * 64 + c0);
        accl.x = fmaf(xk, wl.x, accl.x);
        accl.y = fmaf(xk, wl.y, accl.y);
        accl.z = fmaf(xk, wl.z, accl.z);
        accl.w = fmaf(xk, wl.w, accl.w);
        accr.x = fmaf(xk, wr.x, accr.x);
        accr.y = fmaf(xk, wr.y, accr.y);
        accr.z = fmaf(xk, wr.z, accr.z);
        accr.w = fmaf(xk, wr.w, accr.w);
        accs.x = fmaf(xk, wsv.x, accs.x);
        accs.y = fmaf(xk, wsv.y, accs.y);
        accs.z = fmaf(xk, wsv.z, accs.z);
        accs.w = fmaf(xk, wsv.w, accs.w);
    }
    if (valid) {
        size_t base = (size_t)n * 64 + c0;
        half4v hl, hr, hs;
        hl.x = (_Float16)accl.x; hl.y = (_Float16)accl.y;
        hl.z = (_Float16)accl.z; hl.w = (_Float16)accl.w;
        hr.x = (_Float16)accr.x; hr.y = (_Float16)accr.y;
        hr.z = (_Float16)accr.z; hr.w = (_Float16)accr.w;
        hs.x = (_Float16)relu(accs.x); hs.y = (_Float16)relu(accs.y);
        hs.z = (_Float16)relu(accs.z); hs.w = (_Float16)relu(accs.w);
        *(half4v*)(xlh + base) = hl;
        *(half4v*)(xr16 + base) = hr;
        *(half4v*)(res16 + base) = hs;
    }
}

// ---------- layer 1 precompute: fdot2 (packed fp16 MAC, f32 accum) ----------
__global__ void k_pre1w(const _Float16* __restrict__ h16,
                        const float* __restrict__ Wl, const float* __restrict__ Wr,
                        const float* __restrict__ Wres, const float* __restrict__ bres,
                        _Float16* __restrict__ xlh, _Float16* __restrict__ xr16,
                        _Float16* __restrict__ res16, int N)
{
    __shared__ half4v wl4[16][64];
    __shared__ half4v wr4[16][64];
    __shared__ half4v ws4[16][64];
    __shared__ half4v h4[32][16];
    int tid = threadIdx.x;
    int nb = blockIdx.x * 32;

    for (int idx = tid; idx < 3 * 1024; idx += BLK) {
        int m = idx >> 10, rem = idx & 1023;
        int k4 = rem >> 6, c = rem & 63;
        const float* W = (m == 0) ? Wl : (m == 1) ? Wr : Wres;
        half4v v;
        v.x = (_Float16)W[(4 * k4 + 0) * 64 + c];
        v.y = (_Float16)W[(4 * k4 + 1) * 64 + c];
        v.z = (_Float16)W[(4 * k4 + 2) * 64 + c];
        v.w = (_Float16)W[(4 * k4 + 3) * 64 + c];
        (m == 0 ? wl4 : m == 1 ? wr4 : ws4)[k4][c] = v;
    }
    for (int idx = tid; idx < 512; idx += BLK) {
        int i = idx >> 4, k4 = idx & 15;
        int n = nb + i; if (n >= N) n = N - 1;
        h4[i][k4] = *(const half4v*)(h16 + (size_t)n * 64 + k4 * 4);
    }
    __syncthreads();

    int c = tid & 63, w = tid >> 6;
    float al[8], ar[8], as[8];
    float vbs = bres[c];
    #pragma unroll
    for (int i = 0; i < 8; ++i) { al[i] = 0.f; ar[i] = 0.f; as[i] = vbs; }

    #pragma unroll 4
    for (int k4 = 0; k4 < 16; ++k4) {
        half4v wl = wl4[k4][c];
        half4v wr = wr4[k4][c];
        half4v wsv = ws4[k4][c];
        half2v wll = { wl.x, wl.y },  wlh = { wl.z, wl.w };
        half2v wrl = { wr.x, wr.y },  wrh = { wr.z, wr.w };
        half2v wsl = { wsv.x, wsv.y }, wsh = { wsv.z, wsv.w };
        #pragma unroll
        for (int i = 0; i < 8; ++i) {
            half4v hv = h4[w * 8 + i][k4];   // same-addr broadcast across wave
            half2v hl = { hv.x, hv.y }, hh = { hv.z, hv.w };
            al[i] = FDOT2(hl, wll, al[i]);
            al[i] = FDOT2(hh, wlh, al[i]);
            ar[i] = FDOT2(hl, wrl, ar[i]);
            ar[i] = FDOT2(hh, wrh, ar[i]);
            as[i] = FDOT2(hl, wsl, as[i]);
            as[i] = FDOT2(hh, wsh, as[i]);
        }
    }
    #pragma unroll
    for (int i = 0; i < 8; ++i) {
        int n = nb + w * 8 + i;
        if (n < N) {
            xlh[(size_t)n * 64 + c]   = (_Float16)al[i];
            xr16[(size_t)n * 64 + c]  = (_Float16)ar[i];
            res16[(size_t)n * 64 + c] = (_Float16)relu(as[i]);
        }
    }
}

// ---------- fused GATv2: degree-ranked, packed-fp16 logits, 4-edge batch ----
template <bool DEC>
__global__ void k_gat3(const int* __restrict__ fbeg, const int* __restrict__ fend,
                       const int* __restrict__ srcs,
                       const _Float16* __restrict__ xlh, const _Float16* __restrict__ xr16,
                       const float* __restrict__ att, const float* __restrict__ bias,
                       const _Float16* __restrict__ res16,
                       _Float16* __restrict__ hout16,
                       const float* __restrict__ cond, const float* __restrict__ wcomb,
                       const float* __restrict__ bfinal, float* __restrict__ out,
                       int N)
{
    __shared__ int lh[BDST];
    __shared__ int rp[BDST + 1];
    __shared__ int cc[BDST];
    __shared__ int sidx[BDST];
    __shared__ int tags[FCAP];

    int b = blockIdx.x;
    int tid = threadIdx.x;
    int beg = fbeg[b];
    int nE = fend[b] - beg; if (nE > FCAP) nE = FCAP;

    if (tid < BDST) lh[tid] = 0;
    __syncthreads();
    for (int k = tid; k < nE; k += BLK) atomicAdd(&lh[srcs[beg + k] & 31], 1);
    __syncthreads();
    if (tid == 0) {
        int acc = 0;
        rp[0] = 0;
        #pragma unroll
        for (int i = 0; i < BDST; ++i) { acc += lh[i]; rp[i + 1] = acc; }
    }
    __syncthreads();
    if (tid < BDST) cc[tid] = rp[tid];
    __syncthreads();
    for (int k = tid; k < nE; k += BLK) {
        int tg = srcs[beg + k];
        int r = atomicAdd(&cc[tg & 31], 1);
        tags[r] = tg >> 5;
    }
    // degree-rank: sidx[rank] = dlow, descending degree (ties by index)
    if (tid < BDST) {
        int di = rp[tid + 1] - rp[tid];
        int r = 0;
        #pragma unroll
        for (int j = 0; j < BDST; ++j) {
            int dj = rp[j + 1] - rp[j];
            r += (dj > di) || (dj == di && j < tid);
        }
        sidx[r] = tid;
    }
    __syncthreads();

    int lane = tid & 63, w = tid >> 6;
    int g = lane >> 4, q = lane & 15;
    int c0 = q * 4;
    float4 a4f = *(const float4*)(att + c0);
    const half2v c02 = { (_Float16)0.2f, (_Float16)0.2f };
    half2v alo = { (_Float16)a4f.x, (_Float16)a4f.y };
    half2v ahi = { (_Float16)a4f.z, (_Float16)a4f.w };

    #pragma unroll
    for (int rep = 0; rep < 2; ++rep) {
        int dlow = sidx[w * 8 + rep * 4 + g];   // similar-degree group
        int node = b * BDST + dlow;
        bool nvalid = node < N;
        int n = nvalid ? node : 0;

        half4v xrh = *(const half4v*)(xr16 + (size_t)n * 64 + c0);
        half2v xlo = { xrh.x, xrh.y }, xhi = { xrh.z, xrh.w };

        half4v hsv = *(const half4v*)(xlh + (size_t)n * 64 + c0);
        float lv = edot(hsv, xlo, xhi, alo, ahi, c02);
        lv += __shfl_xor(lv, 1, 8);
        lv += __shfl_xor(lv, 2, 8);
        lv += __shfl_xor(lv, 4, 8);

        float m = lv, den = 1.f;
        float ac0 = (float)hsv.x, ac1 = (float)hsv.y;
        float ac2 = (float)hsv.z, ac3 = (float)hsv.w;

        int deg = nvalid ? (rp[dlow + 1] - rp[dlow]) : 0;
        int base = nvalid ? rp[dlow] : 0;

        int t1 = max(deg, __shfl_xor(deg, 16, 64));
        int wavemax = max(t1, __shfl_xor(t1, 32, 64));

        // 4-deep prefetch
        int i1 = (0 < deg) ? tags[base + 0] : n;
        int i2 = (1 < deg) ? tags[base + 1] : n;
        int i3 = (2 < deg) ? tags[base + 2] : n;
        int i4 = (3 < deg) ? tags[base + 3] : n;
        half4v p1 = *(const half4v*)(xlh + (size_t)i1 * 64 + c0);
        half4v p2 = *(const half4v*)(xlh + (size_t)i2 * 64 + c0);
        half4v p3 = *(const half4v*)(xlh + (size_t)i3 * 64 + c0);
        half4v p4 = *(const half4v*)(xlh + (size_t)i4 * 64 + c0);

        for (int j = 0; j < wavemax; j += 4) {
            bool a1 = j < deg, a2 = j + 1 < deg, a3 = j + 2 < deg, a4b = j + 3 < deg;
            half4v h1 = p1, h2 = p2, h3 = p3, h4 = p4;
            int n1 = (j + 4 < deg) ? tags[base + j + 4] : n;
            int n2 = (j + 5 < deg) ? tags[base + j + 5] : n;
            int n3 = (j + 6 < deg) ? tags[base + j + 6] : n;
            int n4 = (j + 7 < deg) ? tags[base + j + 7] : n;
            p1 = *(const half4v*)(xlh + (size_t)n1 * 64 + c0);
            p2 = *(const half4v*)(xlh + (size_t)n2 * 64 + c0);
            p3 = *(const half4v*)(xlh + (size_t)n3 * 64 + c0);
            p4 = *(const half4v*)(xlh + (size_t)n4 * 64 + c0);

            float e1 = edot(h1, xlo, xhi, alo, ahi, c02);
            float e2 = edot(h2, xlo, xhi, alo, ahi, c02);
            float e3 = edot(h3, xlo, xhi, alo, ahi, c02);
            float e4 = edot(h4, xlo, xhi, alo, ahi, c02);
            e1 += __shfl_xor(e1, 1, 8); e2 += __shfl_xor(e2, 1, 8);
            e3 += __shfl_xor(e3, 1, 8); e4 += __shfl_xor(e4, 1, 8);
            e1 += __shfl_xor(e1, 2, 8); e2 += __shfl_xor(e2, 2, 8);
            e3 += __shfl_xor(e3, 2, 8); e4 += __shfl_xor(e4, 2, 8);
            e1 += __shfl_xor(e1, 4, 8); e2 += __shfl_xor(e2, 4, 8);
            e3 += __shfl_xor(e3, 4, 8); e4 += __shfl_xor(e4, 4, 8);
            if (!a1) e1 = -1e30f;
            if (!a2) e2 = -1e30f;
            if (!a3) e3 = -1e30f;
            if (!a4b) e4 = -1e30f;

            float mn = fmaxf(fmaxf(m, fmaxf(e1, e2)), fmaxf(e3, e4));
            float sc  = __expf(m - mn);
            float ex1 = __expf(e1 - mn);
            float ex2 = __expf(e2 - mn);
            float ex3 = __expf(e3 - mn);
            float ex4 = __expf(e4 - mn);
            den = den * sc + ((ex1 + ex2) + (ex3 + ex4));
            ac0 = fmaf(ex4, (float)h4.x, fmaf(ex3, (float)h3.x,
                  fmaf(ex2, (float)h2.x, fmaf(ex1, (float)h1.x, ac0 * sc))));
            ac1 = fmaf(ex4, (float)h4.y, fmaf(ex3, (float)h3.y,
                  fmaf(ex2, (float)h2.y, fmaf(ex1, (float)h1.y, ac1 * sc))));
            ac2 = fmaf(ex4, (float)h4.z, fmaf(ex3, (float)h3.z,
                  fmaf(ex2, (float)h2.z, fmaf(ex1, (float)h1.z, ac2 * sc))));
            ac3 = fmaf(ex4, (float)h4.w, fmaf(ex3, (float)h3.w,
                  fmaf(ex2, (float)h2.w, fmaf(ex1, (float)h1.w, ac3 * sc))));
            m = mn;
        }

        float inv = 1.f / den;
        half4v rh = *(const half4v*)(res16 + (size_t)n * 64 + c0);
        float h0, h1, h2, h3;
        if (bias) {
            const float4 b4 = *(const float4*)(bias + c0);
            h0 = relu(ac0 * inv + b4.x) + (float)rh.x;
            h1 = relu(ac1 * inv + b4.y) + (float)rh.y;
            h2 = relu(ac2 * inv + b4.z) + (float)rh.z;
            h3 = relu(ac3 * inv + b4.w) + (float)rh.w;
        } else {
            h0 = relu(ac0 * inv) + (float)rh.x;
            h1 = relu(ac1 * inv) + (float)rh.y;
            h2 = relu(ac2 * inv) + (float)rh.z;
            h3 = relu(ac3 * inv) + (float)rh.w;
        }

        if (!DEC) {
            if (nvalid) {
                half4v o;
                o.x = (_Float16)h0; o.y = (_Float16)h1;
                o.z = (_Float16)h2; o.w = (_Float16)h3;
                *(half4v*)(hout16 + (size_t)n * 64 + c0) = o;
            }
        } else {
            float p0 = h0 * wcomb[(c0 + 0) * 2] + h1 * wcomb[(c0 + 1) * 2]
                     + h2 * wcomb[(c0 + 2) * 2] + h3 * wcomb[(c0 + 3) * 2];
            float p1d = h0 * wcomb[(c0 + 0) * 2 + 1] + h1 * wcomb[(c0 + 1) * 2 + 1]
                      + h2 * wcomb[(c0 + 2) * 2 + 1] + h3 * wcomb[(c0 + 3) * 2 + 1];
            if (q < 4) {
                float4 c4 = *(const float4*)(cond + (size_t)n * 16 + q * 4);
                int d0 = 80 + q * 4;
                p0 += c4.x * wcomb[(d0 + 0) * 2] + c4.y * wcomb[(d0 + 1) * 2]
                    + c4.z * wcomb[(d0 + 2) * 2] + c4.w * wcomb[(d0 + 3) * 2];
                p1d += c4.x * wcomb[(d0 + 0) * 2 + 1] + c4.y * wcomb[(d0 + 1) * 2 + 1]
                     + c4.z * wcomb[(d0 + 2) * 2 + 1] + c4.w * wcomb[(d0 + 3) * 2 + 1];
            }
            #pragma unroll
            for (int off = 1; off < 16; off <<= 1) {
                p0 += __shfl_xor(p0, off, 16);
                p1d += __shfl_xor(p1d, off, 16);
            }
            if (q == 0 && nvalid) {
                out[(size_t)n * 2] = p0 + bfinal[0];
                out[(size_t)n * 2 + 1] = p1d + bfinal[1];
            }
        }
    }
}

static inline int gblk(long long threads) { return (int)((threads + BLK - 1) / BLK); }

extern "C" void kernel_launch(void* const* d_in, const int* in_sizes, int n_in,
                              void* d_out, int out_size, void* d_ws, size_t ws_size,
                              hipStream_t stream) {
    const float* x     = (const float*)d_in[0];
    const int*   ei    = (const int*)d_in[1];
    const int*   t     = (const int*)d_in[2];
    const float* cond  = (const float*)d_in[3];
    const float* Wl0   = (const float*)d_in[4];
    const float* bl0   = (const float*)d_in[5];
    const float* Wr0   = (const float*)d_in[6];
    const float* br0   = (const float*)d_in[7];
    const float* att0  = (const float*)d_in[8];
    const float* bias0 = (const float*)d_in[9];
    const float* Wres0 = (const float*)d_in[10];
    const float* bres0 = (const float*)d_in[11];
    const float* Wl1   = (const float*)d_in[12];
    const float* Wr1   = (const float*)d_in[13];
    const float* att1  = (const float*)d_in[14];
    const float* Wres1 = (const float*)d_in[15];
    const float* bres1 = (const float*)d_in[16];
    const float* Wt0   = (const float*)d_in[17];
    const float* bt0   = (const float*)d_in[18];
    const float* Wt1   = (const float*)d_in[19];
    const float* bt1   = (const float*)d_in[20];
    const float* Wfd   = (const float*)d_in[21];
    const float* bfd   = (const float*)d_in[22];
    const float* Wcls  = (const float*)d_in[23];
    const float* bcls  = (const float*)d_in[24];
    float* out = (float*)d_out;

    const int N   = in_sizes[0] / 16;
    const int E   = in_sizes[1] / 2;
    const int NBC = (N + CDST - 1) / CDST;
    const int NBF = (N + BDST - 1) / BDST;

    float* ws = (float*)d_ws;
    size_t o = 0;
    _Float16* hbuf16 = (_Float16*)(ws + o); o += (size_t)N * 32;
    _Float16* xlh    = (_Float16*)(ws + o); o += (size_t)N * 32;
    _Float16* xr16   = (_Float16*)(ws + o); o += (size_t)N * 32;
    _Float16* res16  = (_Float16*)(ws + o); o += (size_t)N * 32;
    float* wcomb = ws + o; o += 192;
    float* bfin  = ws + o; o += 2;
    int* iws     = (int*)(ws + o);
    size_t io = 0;
    int* ccnt  = iws + io; io += NBC_MAX;
    int* cbase = iws + io; io += NBC_MAX + 1;
    int* ccur  = iws + io; io += NBC_MAX;
    int* fbeg  = iws + io; io += NBF;
    int* fend  = iws + io; io += NBF;
    int* part  = iws + io; io += E;
    int* srcs  = iws + io; io += E;

    const int partBlocks = (E + CHUNK - 1) / CHUNK;

    // tiny decoder/time precompute
    k_tiny<<<1, BLK, 0, stream>>>(t, Wt0, bt0, Wt1, bt1, Wfd, bfd, Wcls, bcls, wcomb, bfin);

    // ---- radix partition by destination ----
    k_zeroc<<<gblk(NBC), BLK, 0, stream>>>(ccnt, NBC);
    k_histc<<<partBlocks, BLK, 0, stream>>>(ei, E, NBC, ccnt);
    k_scan<<<1, BLK, 0, stream>>>(ccnt, NBC, E, cbase, ccur);
    k_part<<<partBlocks, BLK, 0, stream>>>(ei, E, NBC, ccur, part);
    k_refine<<<NBC, BLK, 0, stream>>>(cbase, part, NBF, fbeg, fend, srcs);

    // ---- layer 0 ----
    k_pre0f<<<gblk((long long)((N + 3) / 4) * 64), BLK, 0, stream>>>(
        x, Wl0, bl0, Wr0, br0, Wres0, bres0, xlh, xr16, res16, N);
    k_gat3<false><<<NBF, BLK, 0, stream>>>(fbeg, fend, srcs, xlh, xr16, att0, bias0, res16,
                                           hbuf16, nullptr, nullptr, nullptr, nullptr, N);

    // ---- layer 1 (decoder fused) ----
    k_pre1w<<<(N + 31) / 32, BLK, 0, stream>>>(hbuf16, Wl1, Wr1, Wres1, bres1, xlh, xr16, res16, N);
    k_gat3<true><<<NBF, BLK, 0, stream>>>(fbeg, fend, srcs, xlh, xr16, att1, nullptr, res16,
                                          nullptr, cond, wcomb, bfin, out, N);
}